// Round 1
// baseline (3508.648 us; speedup 1.0000x reference)
//
#include <hip/hip_runtime.h>

typedef unsigned short u16;
typedef unsigned int   u32;

// ---- bf16 helpers (bit-level) ----
__device__ __forceinline__ float b2f(u16 v) {
    union { u32 i; float f; } u; u.i = ((u32)v) << 16; return u.f;
}
__device__ __forceinline__ float blo(u32 v) {
    union { u32 i; float f; } u; u.i = v << 16; return u.f;
}
__device__ __forceinline__ float bhi(u32 v) {
    union { u32 i; float f; } u; u.i = v & 0xffff0000u; return u.f;
}
__device__ __forceinline__ u16 f2b(float f) {   // RNE f32 -> bf16
    u32 x = __float_as_uint(f);
    u32 r = (x + 0x7fffu + ((x >> 16) & 1u)) >> 16;
    return (u16)r;
}

// ---- dtype-generic accessors (legacy scalar kernel) ----
template<bool BF16>
__device__ __forceinline__ float g_at(const void* p, size_t i) {
    if constexpr (BF16) return b2f(((const u16*)p)[i]);
    else                return ((const float*)p)[i];
}
template<bool BF16>
__device__ __forceinline__ float2 g_at2(const void* p, size_t i) {  // i even
    if constexpr (BF16) { u32 v = ((const u32*)p)[i >> 1]; return make_float2(blo(v), bhi(v)); }
    else                return ((const float2*)p)[i >> 1];
}
template<bool BF16>
__device__ __forceinline__ void g_st(void* p, size_t i, float v) {
    if constexpr (BF16) ((u16*)p)[i] = f2b(v);
    else                ((float*)p)[i] = v;
}

// Detect packed-bf16 vs fp32 from the boxes buffer (values in (0,1]).
__device__ __forceinline__ bool detect_bf16(const void* boxes) {
    const u32* u = (const u32*)boxes;
    bool ok = true;
#pragma unroll
    for (int i = 0; i < 8; ++i) ok = ok && ((u[i] & 0xFFFFu) <= 0x3F80u);
    return ok;
}

#define HW 512
#define CIN 64
#define ZCROP (16*16*64)
#define ZC1   (8*8*128)

// =====================================================================
// Legacy scalar kernel (fp32 path + bf16 fallback if workspace too small)
// =====================================================================
template<bool BF16>
__global__ __launch_bounds__(256, 2) void mask_head(
    const void* __restrict__ feat, const void* __restrict__ prop,
    const void* __restrict__ boxes, const int* __restrict__ bidx,
    const int* __restrict__ cls,
    const void* __restrict__ w1, const void* __restrict__ b1,
    const void* __restrict__ w2, const void* __restrict__ b2,
    const void* __restrict__ wd1, const void* __restrict__ bd1,
    const void* __restrict__ wd2, const void* __restrict__ bd2,
    const void* __restrict__ wr, const void* __restrict__ br,
    const void* __restrict__ wsc, const void* __restrict__ bsc,
    void* __restrict__ out, int N)
{
    if (detect_bf16(boxes) != BF16) return;

    __shared__ __align__(16) u16  s_crop[ZCROP + 128];
    __shared__ __align__(16) u16  s_c1[ZC1 + 128];
    __shared__ __align__(16) float s_c2[2048];
    __shared__ __align__(16) float s_d1[512];
    __shared__ __align__(16) float s_d2[512];
    __shared__ float s_prop[256];
    __shared__ float s_wy[16], s_wx[16];
    __shared__ int   s_y0[16], s_y1[16], s_x0[16], s_x1[16];
    __shared__ float s_reg[12], s_sc[3];

    const int n = blockIdx.x;
    if (n >= N) return;
    const int t = threadIdx.x;
    const int b = bidx[n];

    const float fy1 = g_at<BF16>(boxes, n*4+0);
    const float fx1 = g_at<BF16>(boxes, n*4+1);
    const float fy2 = g_at<BF16>(boxes, n*4+2);
    const float fx2 = g_at<BF16>(boxes, n*4+3);

    if (t < 16) {
        float g = (float)t * (1.0f / 15.0f);
        float yy = (fy1 + g * (fy2 - fy1)) * (float)(HW - 1);
        float xx = (fx1 + g * (fx2 - fx1)) * (float)(HW - 1);
        float yf = floorf(yy), xf = floorf(xx);
        s_wy[t] = yy - yf;  s_wx[t] = xx - xf;
        int y0 = min(max((int)yf, 0), HW-1);
        int x0 = min(max((int)xf, 0), HW-1);
        s_y0[t] = y0; s_y1[t] = min(y0 + 1, HW-1);
        s_x0[t] = x0; s_x1[t] = min(x0 + 1, HW-1);
    }
    if (t >= 128) s_crop[ZCROP + (t - 128)] = 0;
    if (t < 128)  s_c1[ZC1 + t] = 0;
    __syncthreads();

    {
        int py = t >> 4, px = t & 15;
        size_t pb = (size_t)b * (HW * HW);
        int y0 = s_y0[py], y1 = s_y1[py], x0 = s_x0[px], x1 = s_x1[px];
        float wy = s_wy[py], wx = s_wx[px];
        float p00 = g_at<BF16>(prop, pb + y0*HW + x0);
        float p01 = g_at<BF16>(prop, pb + y0*HW + x1);
        float p10 = g_at<BF16>(prop, pb + y1*HW + x0);
        float p11 = g_at<BF16>(prop, pb + y1*HW + x1);
        float top = p00 * (1.0f - wx) + p01 * wx;
        float bot = p10 * (1.0f - wx) + p11 * wx;
        s_prop[t] = top * (1.0f - wy) + bot * wy;
    }
    __syncthreads();

    {
        size_t fb = (size_t)b * ((size_t)HW * HW * CIN);
        const int ch = t & 63;
        const int wvl = t >> 6;
        for (int it = 0; it < 64; ++it) {
            int pix = it * 4 + wvl;
            int py = pix >> 4, px = pix & 15;
            int y0 = s_y0[py], y1 = s_y1[py], x0 = s_x0[px], x1 = s_x1[px];
            float wy = s_wy[py], wx = s_wx[px];
            float f00 = g_at<BF16>(feat, fb + (size_t)(y0*HW + x0)*CIN + ch);
            float f01 = g_at<BF16>(feat, fb + (size_t)(y0*HW + x1)*CIN + ch);
            float f10 = g_at<BF16>(feat, fb + (size_t)(y1*HW + x0)*CIN + ch);
            float f11 = g_at<BF16>(feat, fb + (size_t)(y1*HW + x1)*CIN + ch);
            float top = f00 * (1.0f - wx) + f01 * wx;
            float bot = f10 * (1.0f - wx) + f11 * wx;
            float v = (top * (1.0f - wy) + bot * wy) * s_prop[pix];
            s_crop[pix * 64 + ch] = f2b(v);
        }
    }
    __syncthreads();

    const int ocp = t & 63;
    const int wv  = t >> 6;

    {
        float2 bb = g_at2<BF16>(b1, 2*ocp);
        for (int it = 0; it < 4; ++it) {
            int g = it * 4 + wv;
            int oy = g >> 1;
            int oxb = (g & 1) * 4;
            float acc[4][2];
            #pragma unroll
            for (int p = 0; p < 4; ++p) { acc[p][0] = 0.f; acc[p][1] = 0.f; }
            #pragma unroll
            for (int ky = 0; ky < 3; ++ky) {
                int y = oy * 2 + ky;
                bool yv = (y < 16);
                #pragma unroll
                for (int kx = 0; kx < 3; ++kx) {
                    int off[4];
                    #pragma unroll
                    for (int p = 0; p < 4; ++p) {
                        int x = (oxb + p) * 2 + kx;
                        off[p] = (yv && x < 16) ? (y*16 + x) * 64 : ZCROP;
                    }
                    size_t wbase = ((size_t)(ky*3 + kx) * 64) * 128 + 2*ocp;
                    #pragma unroll 8
                    for (int ci = 0; ci < 64; ci += 2) {
                        float2 wa = g_at2<BF16>(w1, wbase + (size_t)ci*128);
                        float2 wb = g_at2<BF16>(w1, wbase + (size_t)(ci+1)*128);
                        #pragma unroll
                        for (int p = 0; p < 4; ++p) {
                            u32 cc = *(const u32*)&s_crop[off[p] + ci];
                            float v0 = blo(cc), v1 = bhi(cc);
                            acc[p][0] += v0 * wa.x + v1 * wb.x;
                            acc[p][1] += v0 * wa.y + v1 * wb.y;
                        }
                    }
                }
            }
            #pragma unroll
            for (int p = 0; p < 4; ++p) {
                int opix = oy * 8 + oxb + p;
                s_c1[opix * 128 + 2*ocp    ] = f2b(fmaxf(acc[p][0] + bb.x, 0.f));
                s_c1[opix * 128 + 2*ocp + 1] = f2b(fmaxf(acc[p][1] + bb.y, 0.f));
            }
        }
    }
    __syncthreads();

    {
        float2 bb = g_at2<BF16>(b2, 2*ocp);
        int oy = wv;
        float acc[4][2];
        #pragma unroll
        for (int p = 0; p < 4; ++p) { acc[p][0] = 0.f; acc[p][1] = 0.f; }
        #pragma unroll
        for (int ky = 0; ky < 3; ++ky) {
            int y = oy * 2 + ky;
            bool yv = (y < 8);
            #pragma unroll
            for (int kx = 0; kx < 3; ++kx) {
                int off[4];
                #pragma unroll
                for (int p = 0; p < 4; ++p) {
                    int x = p * 2 + kx;
                    off[p] = (yv && x < 8) ? (y*8 + x) * 128 : ZC1;
                }
                size_t wbase = ((size_t)(ky*3 + kx) * 128) * 128 + 2*ocp;
                #pragma unroll 8
                for (int ci = 0; ci < 128; ci += 2) {
                    float2 wa = g_at2<BF16>(w2, wbase + (size_t)ci*128);
                    float2 wb = g_at2<BF16>(w2, wbase + (size_t)(ci+1)*128);
                    #pragma unroll
                    for (int p = 0; p < 4; ++p) {
                        u32 cc = *(const u32*)&s_c1[off[p] + ci];
                        float v0 = blo(cc), v1 = bhi(cc);
                        acc[p][0] += v0 * wa.x + v1 * wb.x;
                        acc[p][1] += v0 * wa.y + v1 * wb.y;
                    }
                }
            }
        }
        #pragma unroll
        for (int p = 0; p < 4; ++p) {
            int opix = oy * 4 + p;
            s_c2[opix * 128 + 2*ocp    ] = fmaxf(acc[p][0] + bb.x, 0.f);
            s_c2[opix * 128 + 2*ocp + 1] = fmaxf(acc[p][1] + bb.y, 0.f);
        }
    }
    __syncthreads();

    {
        float acc0 = 0.f, acc1 = 0.f;
        for (int i = 0; i < 2048; i += 4) {
            float4 xv = *(const float4*)&s_c2[i];
            float2 u0 = g_at2<BF16>(wd1, (size_t)(i+0)*512 + 2*t);
            float2 u1 = g_at2<BF16>(wd1, (size_t)(i+1)*512 + 2*t);
            float2 u2 = g_at2<BF16>(wd1, (size_t)(i+2)*512 + 2*t);
            float2 u3 = g_at2<BF16>(wd1, (size_t)(i+3)*512 + 2*t);
            acc0 += xv.x*u0.x + xv.y*u1.x + xv.z*u2.x + xv.w*u3.x;
            acc1 += xv.x*u0.y + xv.y*u1.y + xv.z*u2.y + xv.w*u3.y;
        }
        float2 bb = g_at2<BF16>(bd1, 2*t);
        s_d1[2*t    ] = fmaxf(acc0 + bb.x, 0.f);
        s_d1[2*t + 1] = fmaxf(acc1 + bb.y, 0.f);
    }
    __syncthreads();

    {
        float acc0 = 0.f, acc1 = 0.f;
        for (int i = 0; i < 512; i += 4) {
            float4 xv = *(const float4*)&s_d1[i];
            float2 u0 = g_at2<BF16>(wd2, (size_t)(i+0)*512 + 2*t);
            float2 u1 = g_at2<BF16>(wd2, (size_t)(i+1)*512 + 2*t);
            float2 u2 = g_at2<BF16>(wd2, (size_t)(i+2)*512 + 2*t);
            float2 u3 = g_at2<BF16>(wd2, (size_t)(i+3)*512 + 2*t);
            acc0 += xv.x*u0.x + xv.y*u1.x + xv.z*u2.x + xv.w*u3.x;
            acc1 += xv.x*u0.y + xv.y*u1.y + xv.z*u2.y + xv.w*u3.y;
        }
        float2 bb = g_at2<BF16>(bd2, 2*t);
        s_d2[2*t    ] = fmaxf(acc0 + bb.x, 0.f);
        s_d2[2*t + 1] = fmaxf(acc1 + bb.y, 0.f);
    }
    __syncthreads();

    if (t < 12) {
        float a = g_at<BF16>(br, t);
        for (int i = 0; i < 512; ++i) a += s_d2[i] * g_at<BF16>(wr, (size_t)i*12 + t);
        s_reg[t] = a;
    }
    if (t >= 64 && t < 67) {
        int j = t - 64;
        float a = g_at<BF16>(bsc, j);
        for (int i = 0; i < 512; ++i) a += s_d2[i] * g_at<BF16>(wsc, (size_t)i*3 + j);
        s_sc[j] = a;
    }
    __syncthreads();

    if (t == 0) {
        int c = cls[n];
        g_st<BF16>(out, n, s_sc[c]);
        float dy = s_reg[c*4+0], dx = s_reg[c*4+1];
        float dh = s_reg[c*4+2], dw = s_reg[c*4+3];
        g_st<BF16>(out, (size_t)N + n*4 + 0, dy);
        g_st<BF16>(out, (size_t)N + n*4 + 1, dx);
        g_st<BF16>(out, (size_t)N + n*4 + 2, dh);
        g_st<BF16>(out, (size_t)N + n*4 + 3, dw);
        float h = fy2 - fy1, w = fx2 - fx1;
        float cy = fy1 + 0.5f*h + dy*h;
        float cx = fx1 + 0.5f*w + dx*w;
        float nh = h * expf(dh);
        float nw = w * expf(dw);
        g_st<BF16>(out, (size_t)5*N + n*4 + 0, cy - 0.5f*nh);
        g_st<BF16>(out, (size_t)5*N + n*4 + 1, cx - 0.5f*nw);
        g_st<BF16>(out, (size_t)5*N + n*4 + 2, cy + 0.5f*nh);
        g_st<BF16>(out, (size_t)5*N + n*4 + 3, cx + 0.5f*nw);
    }
}

// =====================================================================
// bf16 MFMA fast path
// =====================================================================
typedef __attribute__((ext_vector_type(8))) short bf16x8;   // 8 bf16 = 4 VGPRs
typedef __attribute__((ext_vector_type(4))) float f32x4;

__device__ __forceinline__ f32x4 MFMA16(bf16x8 a, bf16x8 b, f32x4 c) {
    return __builtin_amdgcn_mfma_f32_16x16x32_bf16(a, b, c, 0, 0, 0);
}

// workspace layout (u16 units)
#define WS_W1   0u          // w1 packed  : 73728
#define WS_W2   73728u      // w2 packed  : 147456
#define WS_WD1  221184u     // wd1 packed : 1048576
#define WS_WD2  1269760u    // wd2 packed : 262144
#define WS_X    1531904u    // conv2 out, d1-A-frag layout: NT16*32768

// Fragment packing: packed[((mt*KK + kk)*64 + l)*8 + j] = W[(kk*32 + (l>>4)*8 + j)*C + mt*16 + (l&15)]
// => any A/B fragment is a single 16B per-lane contiguous load.
__device__ __forceinline__ void pack_one(const u16* __restrict__ W, u16* __restrict__ dst,
                                         int bid, int KK, int C) {
    int mt = bid / (KK*64);
    int kk = (bid >> 6) % KK;
    int l  = bid & 63;
    size_t s = (size_t)(kk*32 + ((l>>4)<<3))*C + mt*16 + (l&15);
    u16 tmp[8];
#pragma unroll
    for (int j = 0; j < 8; ++j) tmp[j] = W[s + (size_t)j*C];
    *(uint4*)(dst + (size_t)bid*8) = *(const uint4*)tmp;
}

__global__ __launch_bounds__(256) void pack_weights(
    const void* __restrict__ boxes,
    const void* __restrict__ w1, const void* __restrict__ w2,
    const void* __restrict__ wd1, const void* __restrict__ wd2,
    u16* __restrict__ ws)
{
    if (!detect_bf16(boxes)) return;
    int id = blockIdx.x*256 + threadIdx.x;
    if      (id <   9216) pack_one((const u16*)w1,  ws+WS_W1,  id,          18, 128);
    else if (id <  27648) pack_one((const u16*)w2,  ws+WS_W2,  id-9216,     36, 128);
    else if (id < 158720) pack_one((const u16*)wd1, ws+WS_WD1, id-27648,    64, 512);
    else if (id < 191488) pack_one((const u16*)wd2, ws+WS_WD2, id-158720,   16, 512);
}

// K1: crop+prop-mul -> conv1 (MFMA) -> conv2 (MFMA) -> x_packed (d1 A-frag layout)
// Swapped GEMM: A = W^T (out-ch as M), B = im2col activations (pixels as N),
// so D rows = out-ch (4 consecutive per lane -> 8B packed stores).
__global__ __launch_bounds__(256, 2) void crop_conv(
    const void* __restrict__ feat, const void* __restrict__ prop,
    const void* __restrict__ boxes, const int* __restrict__ bidx,
    const u16* __restrict__ w1p, const u16* __restrict__ w2p,
    const u16* __restrict__ cb1, const u16* __restrict__ cb2,
    u16* __restrict__ xpk, int N)
{
    if (!detect_bf16(boxes)) return;
    // s_crop: 256 pixels x 64ch bf16 (+1 zero row), 128B rows, XOR slot swizzle on bits 4-6
    // s_c1  :  64 pixels x 128ch bf16 (+1 zero row), 256B rows, XOR slot swizzle on bits 4-7
    __shared__ __align__(16) u16 s_crop[257*64];
    __shared__ __align__(16) u16 s_c1[65*128];
    __shared__ float s_prop[256];
    __shared__ float s_wy[16], s_wx[16];
    __shared__ int   s_y0[16], s_y1[16], s_x0[16], s_x1[16];

    const int n = blockIdx.x;
    const int t = threadIdx.x;
    const int b = bidx[n];
    const u16* bx = (const u16*)boxes;
    const float fy1 = b2f(bx[n*4+0]), fx1 = b2f(bx[n*4+1]);
    const float fy2 = b2f(bx[n*4+2]), fx2 = b2f(bx[n*4+3]);

    if (t < 16) {
        float g = (float)t * (1.0f / 15.0f);
        float yy = (fy1 + g * (fy2 - fy1)) * (float)(HW - 1);
        float xx = (fx1 + g * (fx2 - fx1)) * (float)(HW - 1);
        float yf = floorf(yy), xf = floorf(xx);
        s_wy[t] = yy - yf;  s_wx[t] = xx - xf;
        int y0 = min(max((int)yf, 0), HW-1);
        int x0 = min(max((int)xf, 0), HW-1);
        s_y0[t] = y0; s_y1[t] = min(y0 + 1, HW-1);
        s_x0[t] = x0; s_x1[t] = min(x0 + 1, HW-1);
    }
    // zero pad rows (row 256 of s_crop, row 64 of s_c1)
    if (t < 32)              ((u32*)s_crop)[256*32 + t]      = 0;
    if (t >= 64 && t < 128)  ((u32*)s_c1)[64*64 + (t - 64)]  = 0;
    __syncthreads();

    {   // proposal crop
        int py = t >> 4, px = t & 15;
        size_t pb = (size_t)b * (HW * HW);
        int y0 = s_y0[py], y1 = s_y1[py], x0 = s_x0[px], x1 = s_x1[px];
        float wy = s_wy[py], wx = s_wx[px];
        const u16* pp = (const u16*)prop;
        float p00 = b2f(pp[pb + y0*HW + x0]);
        float p01 = b2f(pp[pb + y0*HW + x1]);
        float p10 = b2f(pp[pb + y1*HW + x0]);
        float p11 = b2f(pp[pb + y1*HW + x1]);
        float top = p00*(1.f-wx) + p01*wx;
        float bot = p10*(1.f-wx) + p11*wx;
        s_prop[t] = top*(1.f-wy) + bot*wy;
    }
    __syncthreads();

    {   // feature crop * prop -> s_crop (u32 = 2 channels per load)
        const int cp = t & 31, g = t >> 5;
        const u32* fpp = (const u32*)feat;
        size_t fbl = (((size_t)b * ((size_t)HW*HW*CIN)) >> 1) + cp;
        for (int it = 0; it < 32; ++it) {
            int pix = it*8 + g;
            int py = pix >> 4, px = pix & 15;
            int y0 = s_y0[py], y1 = s_y1[py], x0 = s_x0[px], x1 = s_x1[px];
            float wy = s_wy[py], wx = s_wx[px];
            u32 c00 = fpp[fbl + (size_t)(y0*HW + x0)*32];
            u32 c01 = fpp[fbl + (size_t)(y0*HW + x1)*32];
            u32 c10 = fpp[fbl + (size_t)(y1*HW + x0)*32];
            u32 c11 = fpp[fbl + (size_t)(y1*HW + x1)*32];
            float pv = s_prop[pix];
            float t0 = blo(c00)*(1.f-wx) + blo(c01)*wx;
            float b0 = blo(c10)*(1.f-wx) + blo(c11)*wx;
            float t1 = bhi(c00)*(1.f-wx) + bhi(c01)*wx;
            float b1h= bhi(c10)*(1.f-wx) + bhi(c11)*wx;
            float v0 = (t0*(1.f-wy) + b0*wy) * pv;
            float v1 = (t1*(1.f-wy) + b1h*wy) * pv;
            u32 pk = (u32)f2b(v0) | ((u32)f2b(v1) << 16);
            int off = pix*128 + ((((cp>>2) ^ ((pix>>1)&7)) & 7) << 4) + (cp&3)*4;
            *(u32*)((char*)s_crop + off) = pk;
        }
    }
    __syncthreads();

    const int wv = t >> 6, l = t & 63, ml = l & 15, kg = l >> 4;

    {   // conv1: M=128 out-ch (A=W1^T, global packed), N=64 pixels (B=im2col, LDS), K=576
        f32x4 acc[2][4];
#pragma unroll
        for (int am = 0; am < 2; ++am)
#pragma unroll
            for (int nt = 0; nt < 4; ++nt) acc[am][nt] = (f32x4){0.f,0.f,0.f,0.f};
        const int oyb = (ml>>3)*2, ox2v = (ml&7)*2;
        const u16* aP0 = w1p + (size_t)(wv*2+0)*9216 + (size_t)l*8;
        const u16* aP1 = w1p + (size_t)(wv*2+1)*9216 + (size_t)l*8;
#pragma unroll
        for (int tap = 0; tap < 9; ++tap) {
            const int ky = tap/3, kx = tap%3;
            int bB[4];
            {
                int x = ox2v + kx;
                bool xv = (x < 16);
#pragma unroll
                for (int nt = 0; nt < 4; ++nt) {
                    int y = nt*4 + oyb + ky;
                    int sp = (xv && y < 16) ? (y*16 + x) : 256;
                    bB[nt] = (sp << 7) | (((sp >> 1) & 7) << 4);
                }
            }
#pragma unroll
            for (int h = 0; h < 2; ++h) {
                const int kk = tap*2 + h;
                const int cisb = (h*4 + kg) << 4;
                bf16x8 a0 = *(const bf16x8*)(aP0 + kk*512);
                bf16x8 a1 = *(const bf16x8*)(aP1 + kk*512);
#pragma unroll
                for (int nt = 0; nt < 4; ++nt) {
                    bf16x8 bfr = *(const bf16x8*)((const char*)s_crop + (bB[nt] ^ cisb));
                    acc[0][nt] = MFMA16(a0, bfr, acc[0][nt]);
                    acc[1][nt] = MFMA16(a1, bfr, acc[1][nt]);
                }
            }
        }
        // epilogue: bias+relu -> s_c1 (swizzled, 8B stores of 4 consecutive channels)
#pragma unroll
        for (int am = 0; am < 2; ++am) {
            const int ch0 = wv*32 + am*16 + kg*4;
            float bias[4];
#pragma unroll
            for (int r = 0; r < 4; ++r) bias[r] = b2f(cb1[ch0 + r]);
            const int sl = (ch0 >> 3) << 4;
            const int lo = (ch0 & 7) * 2;
#pragma unroll
            for (int nt = 0; nt < 4; ++nt) {
                int p = nt*16 + ml;
                u16 pk[4];
#pragma unroll
                for (int r = 0; r < 4; ++r) pk[r] = f2b(fmaxf(acc[am][nt][r] + bias[r], 0.f));
                int g2 = ((((p>>1)&3) | (((p>>4)&3)<<2))) << 4;
                int off = p*256 + (sl ^ g2) + lo;
                *(uint2*)((char*)s_c1 + off) = *(const uint2*)pk;
            }
        }
    }
    __syncthreads();

    {   // conv2: M=128 out-ch, N=16 pixels, K=1152
        f32x4 acc[2];
        acc[0] = (f32x4){0.f,0.f,0.f,0.f};
        acc[1] = (f32x4){0.f,0.f,0.f,0.f};
        const int oyb = (ml>>2)*2, ox2v = (ml&3)*2;
        const u16* aP0 = w2p + (size_t)(wv*2+0)*18432 + (size_t)l*8;
        const u16* aP1 = w2p + (size_t)(wv*2+1)*18432 + (size_t)l*8;
#pragma unroll
        for (int tap = 0; tap < 9; ++tap) {
            const int ky = tap/3, kx = tap%3;
            int y = oyb + ky, x = ox2v + kx;
            int sp = (y < 8 && x < 8) ? (y*8 + x) : 64;
            int bB = sp*256 + (((((sp>>1)&3) | (((sp>>4)&3)<<2))) << 4);
#pragma unroll
            for (int q = 0; q < 4; ++q) {
                const int kk = tap*4 + q;
                const int slb = (q*4 + kg) << 4;
                bf16x8 bfr = *(const bf16x8*)((const char*)s_c1 + (bB ^ slb));
                bf16x8 a0 = *(const bf16x8*)(aP0 + kk*512);
                bf16x8 a1 = *(const bf16x8*)(aP1 + kk*512);
                acc[0] = MFMA16(a0, bfr, acc[0]);
                acc[1] = MFMA16(a1, bfr, acc[1]);
            }
        }
        // epilogue: bias+relu -> xpk directly in the d1 A-fragment layout
        const size_t bt = (size_t)(n >> 4), bl = (size_t)(n & 15);
#pragma unroll
        for (int am = 0; am < 2; ++am) {
            const int ch0 = wv*32 + am*16 + kg*4;
            u16 pk[4];
#pragma unroll
            for (int r = 0; r < 4; ++r)
                pk[r] = f2b(fmaxf(acc[am][r] + b2f(cb2[ch0 + r]), 0.f));
            size_t dst = (bt*64 + (size_t)ml*4 + (size_t)(ch0>>5))*512
                       + (size_t)((ch0 & 31) >> 3)*128 + bl*8 + (size_t)(ch0 & 7);
            *(uint2*)(xpk + dst) = *(const uint2*)pk;
        }
    }
}

// K2: d1 (16x2048 x 2048x512) + d2 (16x512 x 512x512) + heads, per 16-box block
__global__ __launch_bounds__(256, 2) void fc_head(
    const void* __restrict__ boxes, const int* __restrict__ cls,
    const u16* __restrict__ xpk,
    const u16* __restrict__ wd1p, const u16* __restrict__ bd1,
    const u16* __restrict__ wd2p, const u16* __restrict__ bd2,
    const u16* __restrict__ wr,  const u16* __restrict__ br,
    const u16* __restrict__ wsc, const u16* __restrict__ bsc,
    void* __restrict__ out, int N)
{
    if (!detect_bf16(boxes)) return;
    __shared__ __align__(16) u16  s_d1[16*512];   // bf16, 1024B rows, XOR slot swizzle
    __shared__ __align__(16) float s_d2[16*516];  // f32, padded rows
    __shared__ __align__(16) u16  s_hw[512*16];   // head weights [i][o]
    __shared__ float s_hb[16];
    __shared__ float s_res[16][16];

    const int bt = blockIdx.x, t = threadIdx.x;
    const int wv = t >> 6, l = t & 63, ml = l & 15, kg = l >> 4;

    {   // d1
        f32x4 acc[8];
#pragma unroll
        for (int i = 0; i < 8; ++i) acc[i] = (f32x4){0.f,0.f,0.f,0.f};
        const u16* aB = xpk  + (size_t)bt*32768 + (size_t)l*8;
        const u16* wB = wd1p + (size_t)(wv*8)*32768 + (size_t)l*8;
#pragma unroll 2
        for (int kk = 0; kk < 64; ++kk) {
            bf16x8 a = *(const bf16x8*)(aB + (size_t)kk*512);
#pragma unroll
            for (int i = 0; i < 8; ++i) {
                bf16x8 w = *(const bf16x8*)(wB + (size_t)i*32768 + (size_t)kk*512);
                acc[i] = MFMA16(a, w, acc[i]);
            }
        }
#pragma unroll
        for (int i = 0; i < 8; ++i) {
            int n0 = wv*128 + i*16 + ml;
            float bias = b2f(bd1[n0]);
            int sl = n0 >> 3;
            int lo = (n0 & 7) * 2;
#pragma unroll
            for (int r = 0; r < 4; ++r) {
                int box = kg*4 + r;
                u16 hv = f2b(fmaxf(acc[i][r] + bias, 0.f));
                *(u16*)((char*)s_d1 + box*1024 + (((sl ^ box) & 63) << 4) + lo) = hv;
            }
        }
    }
    __syncthreads();

    {   // d2
        f32x4 acc[8];
#pragma unroll
        for (int i = 0; i < 8; ++i) acc[i] = (f32x4){0.f,0.f,0.f,0.f};
        const u16* wB = wd2p + (size_t)(wv*8)*8192 + (size_t)l*8;
#pragma unroll 4
        for (int kk = 0; kk < 16; ++kk) {
            int sl = ((kk*4 + kg) ^ ml) & 63;
            bf16x8 a = *(const bf16x8*)((const char*)s_d1 + ml*1024 + (sl << 4));
#pragma unroll
            for (int i = 0; i < 8; ++i) {
                bf16x8 w = *(const bf16x8*)(wB + (size_t)i*8192 + (size_t)kk*512);
                acc[i] = MFMA16(a, w, acc[i]);
            }
        }
#pragma unroll
        for (int i = 0; i < 8; ++i) {
            int n0 = wv*128 + i*16 + ml;
            float bias = b2f(bd2[n0]);
#pragma unroll
            for (int r = 0; r < 4; ++r) {
                int box = kg*4 + r;
                s_d2[box*516 + n0] = fmaxf(acc[i][r] + bias, 0.f);
            }
        }
    }
    // stage head weights: s_hw[i*16+o], o<12 from wr, 12..14 from wsc
    for (int idx = t; idx < 8192; idx += 256) {
        int i = idx >> 4, o = idx & 15;
        u16 v = 0;
        if (o < 12)      v = wr[i*12 + o];
        else if (o < 15) v = wsc[i*3 + o - 12];
        s_hw[idx] = v;
    }
    if (t < 16) s_hb[t] = (t < 12) ? b2f(br[t]) : (t < 15 ? b2f(bsc[t-12]) : 0.f);
    __syncthreads();

    {   // heads: thread (box = t>>4, o = t&15)
        int box = t >> 4, o = t & 15;
        float a = s_hb[o];
        const float* dp = &s_d2[box*516];
        for (int i = 0; i < 512; ++i) a += dp[i] * b2f(s_hw[i*16 + o]);
        s_res[box][o] = a;
    }
    __syncthreads();

    if (t < 16) {
        int n = bt*16 + t;
        if (n < N) {
            int c = cls[n];
            const u16* bx = (const u16*)boxes;
            float fy1 = b2f(bx[n*4+0]), fx1 = b2f(bx[n*4+1]);
            float fy2 = b2f(bx[n*4+2]), fx2 = b2f(bx[n*4+3]);
            float sc = s_res[t][12 + c];
            float dy = s_res[t][c*4+0], dx = s_res[t][c*4+1];
            float dh = s_res[t][c*4+2], dw = s_res[t][c*4+3];
            u16* o16 = (u16*)out;
            o16[n] = f2b(sc);
            o16[N + n*4 + 0] = f2b(dy);
            o16[N + n*4 + 1] = f2b(dx);
            o16[N + n*4 + 2] = f2b(dh);
            o16[N + n*4 + 3] = f2b(dw);
            float h = fy2 - fy1, w = fx2 - fx1;
            float cy = fy1 + 0.5f*h + dy*h;
            float cx = fx1 + 0.5f*w + dx*w;
            float nh = h * expf(dh);
            float nw = w * expf(dw);
            o16[5*N + n*4 + 0] = f2b(cy - 0.5f*nh);
            o16[5*N + n*4 + 1] = f2b(cx - 0.5f*nw);
            o16[5*N + n*4 + 2] = f2b(cy + 0.5f*nh);
            o16[5*N + n*4 + 3] = f2b(cx + 0.5f*nw);
        }
    }
}

extern "C" void kernel_launch(void* const* d_in, const int* in_sizes, int n_in,
                              void* d_out, int out_size, void* d_ws, size_t ws_size,
                              hipStream_t stream) {
    const void* feat  = d_in[0];
    const void* prop  = d_in[1];
    const void* boxes = d_in[2];
    const int*  bidx  = (const int*)d_in[3];
    const int*  cls   = (const int*)d_in[4];
    const void* w1  = d_in[5];
    const void* b1  = d_in[6];
    const void* w2  = d_in[7];
    const void* b2  = d_in[8];
    const void* wd1 = d_in[9];
    const void* bd1 = d_in[10];
    const void* wd2 = d_in[11];
    const void* bd2 = d_in[12];
    const void* wr  = d_in[13];
    const void* br  = d_in[14];
    const void* wsc = d_in[15];
    const void* bsc = d_in[16];
    const int N = in_sizes[3];   // boxes
    const int NT16 = (N + 15) / 16;
    const size_t need_bytes = ((size_t)WS_X + (size_t)NT16 * 32768) * 2;

    if (N > 0 && ws_size >= need_bytes) {
        u16* ws = (u16*)d_ws;
        // bf16 fast path (self-gated on detected dtype inside each kernel)
        pack_weights<<<748, 256, 0, stream>>>(boxes, w1, w2, wd1, wd2, ws);
        crop_conv<<<N, 256, 0, stream>>>(feat, prop, boxes, bidx,
                                         ws + WS_W1, ws + WS_W2,
                                         (const u16*)b1, (const u16*)b2,
                                         ws + WS_X, N);
        fc_head<<<NT16, 256, 0, stream>>>(boxes, cls, ws + WS_X,
                                          ws + WS_WD1, (const u16*)bd1,
                                          ws + WS_WD2, (const u16*)bd2,
                                          (const u16*)wr, (const u16*)br,
                                          (const u16*)wsc, (const u16*)bsc,
                                          d_out, N);
    } else {
        // no workspace: legacy bf16 kernel
        mask_head<true ><<<N, 256, 0, stream>>>(feat, prop, boxes, bidx, cls,
                                                w1, b1, w2, b2, wd1, bd1, wd2, bd2,
                                                wr, br, wsc, bsc, d_out, N);
    }
    // fp32 path (self-gated; no-ops when inputs are bf16)
    mask_head<false><<<N, 256, 0, stream>>>(feat, prop, boxes, bidx, cls,
                                            w1, b1, w2, b2, wd1, bd1, wd2, bd2,
                                            wr, br, wsc, bsc, d_out, N);
}

// Round 2
// 887.310 us; speedup vs baseline: 3.9543x; 3.9543x over previous
//
#include <hip/hip_runtime.h>

typedef unsigned short u16;
typedef unsigned int   u32;

// ---- bf16 helpers (bit-level) ----
__device__ __forceinline__ float b2f(u16 v) {
    union { u32 i; float f; } u; u.i = ((u32)v) << 16; return u.f;
}
__device__ __forceinline__ float blo(u32 v) {
    union { u32 i; float f; } u; u.i = v << 16; return u.f;
}
__device__ __forceinline__ float bhi(u32 v) {
    union { u32 i; float f; } u; u.i = v & 0xffff0000u; return u.f;
}
__device__ __forceinline__ u16 f2b(float f) {   // RNE f32 -> bf16
    u32 x = __float_as_uint(f);
    u32 r = (x + 0x7fffu + ((x >> 16) & 1u)) >> 16;
    return (u16)r;
}

// ---- dtype-generic accessors ----
template<bool BF16>
__device__ __forceinline__ float g_at(const void* p, size_t i) {
    if constexpr (BF16) return b2f(((const u16*)p)[i]);
    else                return ((const float*)p)[i];
}
template<bool BF16>
__device__ __forceinline__ float2 g_at2(const void* p, size_t i) {  // i even
    if constexpr (BF16) { u32 v = ((const u32*)p)[i >> 1]; return make_float2(blo(v), bhi(v)); }
    else                return ((const float2*)p)[i >> 1];
}
// load channel-pair (2 consecutive elements) at pair index
template<bool BF16>
__device__ __forceinline__ float2 ld_pair(const void* p, size_t pairIdx) {
    if constexpr (BF16) { u32 v = ((const u32*)p)[pairIdx]; return make_float2(blo(v), bhi(v)); }
    else                return ((const float2*)p)[pairIdx];
}
template<bool BF16>
__device__ __forceinline__ void g_st(void* p, size_t i, float v) {
    if constexpr (BF16) ((u16*)p)[i] = f2b(v);
    else                ((float*)p)[i] = v;
}

// Detect packed-bf16 vs fp32 from the boxes buffer (values in (0,1]).
__device__ __forceinline__ bool detect_bf16(const void* boxes) {
    const u32* u = (const u32*)boxes;
    bool ok = true;
#pragma unroll
    for (int i = 0; i < 8; ++i) ok = ok && ((u[i] & 0xFFFFu) <= 0x3F80u);
    return ok;
}

#define HW 512
#define CIN 64
#define ZCROP (16*16*64)
#define ZC1   (8*8*128)

// =====================================================================
// Legacy scalar kernel (fallback when workspace is too small)
// =====================================================================
template<bool BF16>
__global__ __launch_bounds__(256, 2) void mask_head(
    const void* __restrict__ feat, const void* __restrict__ prop,
    const void* __restrict__ boxes, const int* __restrict__ bidx,
    const int* __restrict__ cls,
    const void* __restrict__ w1, const void* __restrict__ b1,
    const void* __restrict__ w2, const void* __restrict__ b2,
    const void* __restrict__ wd1, const void* __restrict__ bd1,
    const void* __restrict__ wd2, const void* __restrict__ bd2,
    const void* __restrict__ wr, const void* __restrict__ br,
    const void* __restrict__ wsc, const void* __restrict__ bsc,
    void* __restrict__ out, int N)
{
    if (detect_bf16(boxes) != BF16) return;

    __shared__ __align__(16) u16  s_crop[ZCROP + 128];
    __shared__ __align__(16) u16  s_c1[ZC1 + 128];
    __shared__ __align__(16) float s_c2[2048];
    __shared__ __align__(16) float s_d1[512];
    __shared__ __align__(16) float s_d2[512];
    __shared__ float s_prop[256];
    __shared__ float s_wy[16], s_wx[16];
    __shared__ int   s_y0[16], s_y1[16], s_x0[16], s_x1[16];
    __shared__ float s_reg[12], s_sc[3];

    const int n = blockIdx.x;
    if (n >= N) return;
    const int t = threadIdx.x;
    const int b = bidx[n];

    const float fy1 = g_at<BF16>(boxes, n*4+0);
    const float fx1 = g_at<BF16>(boxes, n*4+1);
    const float fy2 = g_at<BF16>(boxes, n*4+2);
    const float fx2 = g_at<BF16>(boxes, n*4+3);

    if (t < 16) {
        float g = (float)t * (1.0f / 15.0f);
        float yy = (fy1 + g * (fy2 - fy1)) * (float)(HW - 1);
        float xx = (fx1 + g * (fx2 - fx1)) * (float)(HW - 1);
        float yf = floorf(yy), xf = floorf(xx);
        s_wy[t] = yy - yf;  s_wx[t] = xx - xf;
        int y0 = min(max((int)yf, 0), HW-1);
        int x0 = min(max((int)xf, 0), HW-1);
        s_y0[t] = y0; s_y1[t] = min(y0 + 1, HW-1);
        s_x0[t] = x0; s_x1[t] = min(x0 + 1, HW-1);
    }
    if (t >= 128) s_crop[ZCROP + (t - 128)] = 0;
    if (t < 128)  s_c1[ZC1 + t] = 0;
    __syncthreads();

    {
        int py = t >> 4, px = t & 15;
        size_t pb = (size_t)b * (HW * HW);
        int y0 = s_y0[py], y1 = s_y1[py], x0 = s_x0[px], x1 = s_x1[px];
        float wy = s_wy[py], wx = s_wx[px];
        float p00 = g_at<BF16>(prop, pb + y0*HW + x0);
        float p01 = g_at<BF16>(prop, pb + y0*HW + x1);
        float p10 = g_at<BF16>(prop, pb + y1*HW + x0);
        float p11 = g_at<BF16>(prop, pb + y1*HW + x1);
        float top = p00 * (1.0f - wx) + p01 * wx;
        float bot = p10 * (1.0f - wx) + p11 * wx;
        s_prop[t] = top * (1.0f - wy) + bot * wy;
    }
    __syncthreads();

    {
        size_t fb = (size_t)b * ((size_t)HW * HW * CIN);
        const int ch = t & 63;
        const int wvl = t >> 6;
        for (int it = 0; it < 64; ++it) {
            int pix = it * 4 + wvl;
            int py = pix >> 4, px = pix & 15;
            int y0 = s_y0[py], y1 = s_y1[py], x0 = s_x0[px], x1 = s_x1[px];
            float wy = s_wy[py], wx = s_wx[px];
            float f00 = g_at<BF16>(feat, fb + (size_t)(y0*HW + x0)*CIN + ch);
            float f01 = g_at<BF16>(feat, fb + (size_t)(y0*HW + x1)*CIN + ch);
            float f10 = g_at<BF16>(feat, fb + (size_t)(y1*HW + x0)*CIN + ch);
            float f11 = g_at<BF16>(feat, fb + (size_t)(y1*HW + x1)*CIN + ch);
            float top = f00 * (1.0f - wx) + f01 * wx;
            float bot = f10 * (1.0f - wx) + f11 * wx;
            float v = (top * (1.0f - wy) + bot * wy) * s_prop[pix];
            s_crop[pix * 64 + ch] = f2b(v);
        }
    }
    __syncthreads();

    const int ocp = t & 63;
    const int wv  = t >> 6;

    {
        float2 bb = g_at2<BF16>(b1, 2*ocp);
        for (int it = 0; it < 4; ++it) {
            int g = it * 4 + wv;
            int oy = g >> 1;
            int oxb = (g & 1) * 4;
            float acc[4][2];
            #pragma unroll
            for (int p = 0; p < 4; ++p) { acc[p][0] = 0.f; acc[p][1] = 0.f; }
            #pragma unroll
            for (int ky = 0; ky < 3; ++ky) {
                int y = oy * 2 + ky;
                bool yv = (y < 16);
                #pragma unroll
                for (int kx = 0; kx < 3; ++kx) {
                    int off[4];
                    #pragma unroll
                    for (int p = 0; p < 4; ++p) {
                        int x = (oxb + p) * 2 + kx;
                        off[p] = (yv && x < 16) ? (y*16 + x) * 64 : ZCROP;
                    }
                    size_t wbase = ((size_t)(ky*3 + kx) * 64) * 128 + 2*ocp;
                    #pragma unroll 8
                    for (int ci = 0; ci < 64; ci += 2) {
                        float2 wa = g_at2<BF16>(w1, wbase + (size_t)ci*128);
                        float2 wb = g_at2<BF16>(w1, wbase + (size_t)(ci+1)*128);
                        #pragma unroll
                        for (int p = 0; p < 4; ++p) {
                            u32 cc = *(const u32*)&s_crop[off[p] + ci];
                            float v0 = blo(cc), v1 = bhi(cc);
                            acc[p][0] += v0 * wa.x + v1 * wb.x;
                            acc[p][1] += v0 * wa.y + v1 * wb.y;
                        }
                    }
                }
            }
            #pragma unroll
            for (int p = 0; p < 4; ++p) {
                int opix = oy * 8 + oxb + p;
                s_c1[opix * 128 + 2*ocp    ] = f2b(fmaxf(acc[p][0] + bb.x, 0.f));
                s_c1[opix * 128 + 2*ocp + 1] = f2b(fmaxf(acc[p][1] + bb.y, 0.f));
            }
        }
    }
    __syncthreads();

    {
        float2 bb = g_at2<BF16>(b2, 2*ocp);
        int oy = wv;
        float acc[4][2];
        #pragma unroll
        for (int p = 0; p < 4; ++p) { acc[p][0] = 0.f; acc[p][1] = 0.f; }
        #pragma unroll
        for (int ky = 0; ky < 3; ++ky) {
            int y = oy * 2 + ky;
            bool yv = (y < 8);
            #pragma unroll
            for (int kx = 0; kx < 3; ++kx) {
                int off[4];
                #pragma unroll
                for (int p = 0; p < 4; ++p) {
                    int x = p * 2 + kx;
                    off[p] = (yv && x < 8) ? (y*8 + x) * 128 : ZC1;
                }
                size_t wbase = ((size_t)(ky*3 + kx) * 128) * 128 + 2*ocp;
                #pragma unroll 8
                for (int ci = 0; ci < 128; ci += 2) {
                    float2 wa = g_at2<BF16>(w2, wbase + (size_t)ci*128);
                    float2 wb = g_at2<BF16>(w2, wbase + (size_t)(ci+1)*128);
                    #pragma unroll
                    for (int p = 0; p < 4; ++p) {
                        u32 cc = *(const u32*)&s_c1[off[p] + ci];
                        float v0 = blo(cc), v1 = bhi(cc);
                        acc[p][0] += v0 * wa.x + v1 * wb.x;
                        acc[p][1] += v0 * wa.y + v1 * wb.y;
                    }
                }
            }
        }
        #pragma unroll
        for (int p = 0; p < 4; ++p) {
            int opix = oy * 4 + p;
            s_c2[opix * 128 + 2*ocp    ] = fmaxf(acc[p][0] + bb.x, 0.f);
            s_c2[opix * 128 + 2*ocp + 1] = fmaxf(acc[p][1] + bb.y, 0.f);
        }
    }
    __syncthreads();

    {
        float acc0 = 0.f, acc1 = 0.f;
        for (int i = 0; i < 2048; i += 4) {
            float4 xv = *(const float4*)&s_c2[i];
            float2 u0 = g_at2<BF16>(wd1, (size_t)(i+0)*512 + 2*t);
            float2 u1 = g_at2<BF16>(wd1, (size_t)(i+1)*512 + 2*t);
            float2 u2 = g_at2<BF16>(wd1, (size_t)(i+2)*512 + 2*t);
            float2 u3 = g_at2<BF16>(wd1, (size_t)(i+3)*512 + 2*t);
            acc0 += xv.x*u0.x + xv.y*u1.x + xv.z*u2.x + xv.w*u3.x;
            acc1 += xv.x*u0.y + xv.y*u1.y + xv.z*u2.y + xv.w*u3.y;
        }
        float2 bb = g_at2<BF16>(bd1, 2*t);
        s_d1[2*t    ] = fmaxf(acc0 + bb.x, 0.f);
        s_d1[2*t + 1] = fmaxf(acc1 + bb.y, 0.f);
    }
    __syncthreads();

    {
        float acc0 = 0.f, acc1 = 0.f;
        for (int i = 0; i < 512; i += 4) {
            float4 xv = *(const float4*)&s_d1[i];
            float2 u0 = g_at2<BF16>(wd2, (size_t)(i+0)*512 + 2*t);
            float2 u1 = g_at2<BF16>(wd2, (size_t)(i+1)*512 + 2*t);
            float2 u2 = g_at2<BF16>(wd2, (size_t)(i+2)*512 + 2*t);
            float2 u3 = g_at2<BF16>(wd2, (size_t)(i+3)*512 + 2*t);
            acc0 += xv.x*u0.x + xv.y*u1.x + xv.z*u2.x + xv.w*u3.x;
            acc1 += xv.x*u0.y + xv.y*u1.y + xv.z*u2.y + xv.w*u3.y;
        }
        float2 bb = g_at2<BF16>(bd2, 2*t);
        s_d2[2*t    ] = fmaxf(acc0 + bb.x, 0.f);
        s_d2[2*t + 1] = fmaxf(acc1 + bb.y, 0.f);
    }
    __syncthreads();

    if (t < 12) {
        float a = g_at<BF16>(br, t);
        for (int i = 0; i < 512; ++i) a += s_d2[i] * g_at<BF16>(wr, (size_t)i*12 + t);
        s_reg[t] = a;
    }
    if (t >= 64 && t < 67) {
        int j = t - 64;
        float a = g_at<BF16>(bsc, j);
        for (int i = 0; i < 512; ++i) a += s_d2[i] * g_at<BF16>(wsc, (size_t)i*3 + j);
        s_sc[j] = a;
    }
    __syncthreads();

    if (t == 0) {
        int c = cls[n];
        g_st<BF16>(out, n, s_sc[c]);
        float dy = s_reg[c*4+0], dx = s_reg[c*4+1];
        float dh = s_reg[c*4+2], dw = s_reg[c*4+3];
        g_st<BF16>(out, (size_t)N + n*4 + 0, dy);
        g_st<BF16>(out, (size_t)N + n*4 + 1, dx);
        g_st<BF16>(out, (size_t)N + n*4 + 2, dh);
        g_st<BF16>(out, (size_t)N + n*4 + 3, dw);
        float h = fy2 - fy1, w = fx2 - fx1;
        float cy = fy1 + 0.5f*h + dy*h;
        float cx = fx1 + 0.5f*w + dx*w;
        float nh = h * expf(dh);
        float nw = w * expf(dw);
        g_st<BF16>(out, (size_t)5*N + n*4 + 0, cy - 0.5f*nh);
        g_st<BF16>(out, (size_t)5*N + n*4 + 1, cx - 0.5f*nw);
        g_st<BF16>(out, (size_t)5*N + n*4 + 2, cy + 0.5f*nh);
        g_st<BF16>(out, (size_t)5*N + n*4 + 3, cx + 0.5f*nw);
    }
}

// =====================================================================
// MFMA fast path (works for both input dtypes; converts to bf16 on the fly)
// =====================================================================
typedef __attribute__((ext_vector_type(8))) short bf16x8;   // 8 bf16 = 4 VGPRs
typedef __attribute__((ext_vector_type(4))) float f32x4;

__device__ __forceinline__ f32x4 MFMA16(bf16x8 a, bf16x8 b, f32x4 c) {
    return __builtin_amdgcn_mfma_f32_16x16x32_bf16(a, b, c, 0, 0, 0);
}

// workspace layout (u16 units)
#define WS_W1   0u          // w1 packed  : 73728
#define WS_W2   73728u      // w2 packed  : 147456
#define WS_WD1  221184u     // wd1 packed : 1048576
#define WS_WD2  1269760u    // wd2 packed : 262144
#define WS_X    1531904u    // conv2 out, d1-A-frag layout: tiles*32768

// Fragment packing: packed[((mt*KK + kk)*64 + l)*8 + j] = W[(kk*32 + (l>>4)*8 + j)*C + mt*16 + (l&15)]
template<bool BF16>
__device__ __forceinline__ void pack_one(const void* __restrict__ W, u16* __restrict__ dst,
                                         int bid, int KK, int C) {
    int mt = bid / (KK*64);
    int kk = (bid >> 6) % KK;
    int l  = bid & 63;
    size_t s = (size_t)(kk*32 + ((l>>4)<<3))*C + mt*16 + (l&15);
    u16 tmp[8];
#pragma unroll
    for (int j = 0; j < 8; ++j) tmp[j] = f2b(g_at<BF16>(W, s + (size_t)j*C));
    *(uint4*)(dst + (size_t)bid*8) = *(const uint4*)tmp;
}

template<bool BF16>
__global__ __launch_bounds__(256) void pack_weights(
    const void* __restrict__ boxes,
    const void* __restrict__ w1, const void* __restrict__ w2,
    const void* __restrict__ wd1, const void* __restrict__ wd2,
    u16* __restrict__ ws)
{
    if (detect_bf16(boxes) != BF16) return;
    int id = blockIdx.x*256 + threadIdx.x;
    if      (id <   9216) pack_one<BF16>(w1,  ws+WS_W1,  id,          18, 128);
    else if (id <  27648) pack_one<BF16>(w2,  ws+WS_W2,  id-9216,     36, 128);
    else if (id < 158720) pack_one<BF16>(wd1, ws+WS_WD1, id-27648,    64, 512);
    else if (id < 191488) pack_one<BF16>(wd2, ws+WS_WD2, id-158720,   16, 512);
}

// K1: crop+prop-mul -> conv1 (MFMA) -> conv2 (MFMA) -> x_packed (d1 A-frag layout)
template<bool BF16>
__global__ __launch_bounds__(256, 2) void crop_conv(
    const void* __restrict__ feat, const void* __restrict__ prop,
    const void* __restrict__ boxes, const int* __restrict__ bidx,
    const u16* __restrict__ w1p, const u16* __restrict__ w2p,
    const void* __restrict__ cb1, const void* __restrict__ cb2,
    u16* __restrict__ xpk, int n0, int N)
{
    if (detect_bf16(boxes) != BF16) return;
    __shared__ __align__(16) u16 s_crop[257*64];
    __shared__ __align__(16) u16 s_c1[65*128];
    __shared__ float s_prop[256];
    __shared__ float s_wy[16], s_wx[16];
    __shared__ int   s_y0[16], s_y1[16], s_x0[16], s_x1[16];

    const int nloc = blockIdx.x;
    const int n = n0 + nloc;
    const int t = threadIdx.x;
    const int b = bidx[n];
    const float fy1 = g_at<BF16>(boxes, (size_t)n*4+0);
    const float fx1 = g_at<BF16>(boxes, (size_t)n*4+1);
    const float fy2 = g_at<BF16>(boxes, (size_t)n*4+2);
    const float fx2 = g_at<BF16>(boxes, (size_t)n*4+3);

    if (t < 16) {
        float g = (float)t * (1.0f / 15.0f);
        float yy = (fy1 + g * (fy2 - fy1)) * (float)(HW - 1);
        float xx = (fx1 + g * (fx2 - fx1)) * (float)(HW - 1);
        float yf = floorf(yy), xf = floorf(xx);
        s_wy[t] = yy - yf;  s_wx[t] = xx - xf;
        int y0 = min(max((int)yf, 0), HW-1);
        int x0 = min(max((int)xf, 0), HW-1);
        s_y0[t] = y0; s_y1[t] = min(y0 + 1, HW-1);
        s_x0[t] = x0; s_x1[t] = min(x0 + 1, HW-1);
    }
    // zero pad rows (row 256 of s_crop, row 64 of s_c1)
    if (t < 32)              ((u32*)s_crop)[256*32 + t]      = 0;
    if (t >= 64 && t < 128)  ((u32*)s_c1)[64*64 + (t - 64)]  = 0;
    __syncthreads();

    {   // proposal crop
        int py = t >> 4, px = t & 15;
        size_t pb = (size_t)b * (HW * HW);
        int y0 = s_y0[py], y1 = s_y1[py], x0 = s_x0[px], x1 = s_x1[px];
        float wy = s_wy[py], wx = s_wx[px];
        float p00 = g_at<BF16>(prop, pb + y0*HW + x0);
        float p01 = g_at<BF16>(prop, pb + y0*HW + x1);
        float p10 = g_at<BF16>(prop, pb + y1*HW + x0);
        float p11 = g_at<BF16>(prop, pb + y1*HW + x1);
        float top = p00*(1.f-wx) + p01*wx;
        float bot = p10*(1.f-wx) + p11*wx;
        s_prop[t] = top*(1.f-wy) + bot*wy;
    }
    __syncthreads();

    {   // feature crop * prop -> s_crop (pair = 2 channels per load)
        const int cp = t & 31, g = t >> 5;
        size_t fbl = (((size_t)b * ((size_t)HW*HW*CIN)) >> 1) + cp;  // pair units
        for (int it = 0; it < 32; ++it) {
            int pix = it*8 + g;
            int py = pix >> 4, px = pix & 15;
            int y0 = s_y0[py], y1 = s_y1[py], x0 = s_x0[px], x1 = s_x1[px];
            float wy = s_wy[py], wx = s_wx[px];
            float2 c00 = ld_pair<BF16>(feat, fbl + (size_t)(y0*HW + x0)*32);
            float2 c01 = ld_pair<BF16>(feat, fbl + (size_t)(y0*HW + x1)*32);
            float2 c10 = ld_pair<BF16>(feat, fbl + (size_t)(y1*HW + x0)*32);
            float2 c11 = ld_pair<BF16>(feat, fbl + (size_t)(y1*HW + x1)*32);
            float pv = s_prop[pix];
            float t0 = c00.x*(1.f-wx) + c01.x*wx;
            float b0 = c10.x*(1.f-wx) + c11.x*wx;
            float t1 = c00.y*(1.f-wx) + c01.y*wx;
            float b1h= c10.y*(1.f-wx) + c11.y*wx;
            float v0 = (t0*(1.f-wy) + b0*wy) * pv;
            float v1 = (t1*(1.f-wy) + b1h*wy) * pv;
            u32 pk = (u32)f2b(v0) | ((u32)f2b(v1) << 16);
            int off = pix*128 + ((((cp>>2) ^ ((pix>>1)&7)) & 7) << 4) + (cp&3)*4;
            *(u32*)((char*)s_crop + off) = pk;
        }
    }
    __syncthreads();

    const int wv = t >> 6, l = t & 63, ml = l & 15, kg = l >> 4;

    {   // conv1: M=128 out-ch (A=W1^T, global packed), N=64 pixels (B=im2col, LDS), K=576
        f32x4 acc[2][4];
#pragma unroll
        for (int am = 0; am < 2; ++am)
#pragma unroll
            for (int nt = 0; nt < 4; ++nt) acc[am][nt] = (f32x4){0.f,0.f,0.f,0.f};
        const int oyb = (ml>>3)*2, ox2v = (ml&7)*2;
        const u16* aP0 = w1p + (size_t)(wv*2+0)*9216 + (size_t)l*8;
        const u16* aP1 = w1p + (size_t)(wv*2+1)*9216 + (size_t)l*8;
#pragma unroll
        for (int tap = 0; tap < 9; ++tap) {
            const int ky = tap/3, kx = tap%3;
            int bB[4];
            {
                int x = ox2v + kx;
                bool xv = (x < 16);
#pragma unroll
                for (int nt = 0; nt < 4; ++nt) {
                    int y = nt*4 + oyb + ky;
                    int sp = (xv && y < 16) ? (y*16 + x) : 256;
                    bB[nt] = (sp << 7) | (((sp >> 1) & 7) << 4);
                }
            }
#pragma unroll
            for (int h = 0; h < 2; ++h) {
                const int kk = tap*2 + h;
                const int cisb = (h*4 + kg) << 4;
                bf16x8 a0 = *(const bf16x8*)(aP0 + kk*512);
                bf16x8 a1 = *(const bf16x8*)(aP1 + kk*512);
#pragma unroll
                for (int nt = 0; nt < 4; ++nt) {
                    bf16x8 bfr = *(const bf16x8*)((const char*)s_crop + (bB[nt] ^ cisb));
                    acc[0][nt] = MFMA16(a0, bfr, acc[0][nt]);
                    acc[1][nt] = MFMA16(a1, bfr, acc[1][nt]);
                }
            }
        }
        // epilogue: bias+relu -> s_c1 (swizzled, 8B stores of 4 consecutive channels)
#pragma unroll
        for (int am = 0; am < 2; ++am) {
            const int ch0 = wv*32 + am*16 + kg*4;
            float bias[4];
#pragma unroll
            for (int r = 0; r < 4; ++r) bias[r] = g_at<BF16>(cb1, ch0 + r);
            const int sl = (ch0 >> 3) << 4;
            const int lo = (ch0 & 7) * 2;
#pragma unroll
            for (int nt = 0; nt < 4; ++nt) {
                int p = nt*16 + ml;
                u16 pk[4];
#pragma unroll
                for (int r = 0; r < 4; ++r) pk[r] = f2b(fmaxf(acc[am][nt][r] + bias[r], 0.f));
                int g2 = ((((p>>1)&3) | (((p>>4)&3)<<2))) << 4;
                int off = p*256 + (sl ^ g2) + lo;
                *(uint2*)((char*)s_c1 + off) = *(const uint2*)pk;
            }
        }
    }
    __syncthreads();

    {   // conv2: M=128 out-ch, N=16 pixels, K=1152
        f32x4 acc[2];
        acc[0] = (f32x4){0.f,0.f,0.f,0.f};
        acc[1] = (f32x4){0.f,0.f,0.f,0.f};
        const int oyb = (ml>>2)*2, ox2v = (ml&3)*2;
        const u16* aP0 = w2p + (size_t)(wv*2+0)*18432 + (size_t)l*8;
        const u16* aP1 = w2p + (size_t)(wv*2+1)*18432 + (size_t)l*8;
#pragma unroll
        for (int tap = 0; tap < 9; ++tap) {
            const int ky = tap/3, kx = tap%3;
            int y = oyb + ky, x = ox2v + kx;
            int sp = (y < 8 && x < 8) ? (y*8 + x) : 64;
            int bB = sp*256 + (((((sp>>1)&3) | (((sp>>4)&3)<<2))) << 4);
#pragma unroll
            for (int q = 0; q < 4; ++q) {
                const int kk = tap*4 + q;
                const int slb = (q*4 + kg) << 4;
                bf16x8 bfr = *(const bf16x8*)((const char*)s_c1 + (bB ^ slb));
                bf16x8 a0 = *(const bf16x8*)(aP0 + kk*512);
                bf16x8 a1 = *(const bf16x8*)(aP1 + kk*512);
                acc[0] = MFMA16(a0, bfr, acc[0]);
                acc[1] = MFMA16(a1, bfr, acc[1]);
            }
        }
        // epilogue: bias+relu -> xpk directly in the d1 A-fragment layout
        const size_t bt = (size_t)(nloc >> 4), bl = (size_t)(nloc & 15);
#pragma unroll
        for (int am = 0; am < 2; ++am) {
            const int ch0 = wv*32 + am*16 + kg*4;
            u16 pk[4];
#pragma unroll
            for (int r = 0; r < 4; ++r)
                pk[r] = f2b(fmaxf(acc[am][r] + g_at<BF16>(cb2, ch0 + r), 0.f));
            size_t dst = (bt*64 + (size_t)ml*4 + (size_t)(ch0>>5))*512
                       + (size_t)((ch0 & 31) >> 3)*128 + bl*8 + (size_t)(ch0 & 7);
            *(uint2*)(xpk + dst) = *(const uint2*)pk;
        }
    }
}

// K2: d1 (16x2048 x 2048x512) + d2 (16x512 x 512x512) + heads, per 16-box tile
template<bool BF16>
__global__ __launch_bounds__(256, 2) void fc_head(
    const void* __restrict__ boxes, const int* __restrict__ cls,
    const u16* __restrict__ xpk,
    const u16* __restrict__ wd1p, const void* __restrict__ bd1,
    const u16* __restrict__ wd2p, const void* __restrict__ bd2,
    const void* __restrict__ wr,  const void* __restrict__ br,
    const void* __restrict__ wsc, const void* __restrict__ bsc,
    void* __restrict__ out, int n0, int N)
{
    if (detect_bf16(boxes) != BF16) return;
    __shared__ __align__(16) u16  s_d1[16*512];   // bf16, 1024B rows, XOR slot swizzle
    __shared__ __align__(16) float s_d2[16*516];  // f32, padded rows
    __shared__ __align__(16) u16  s_hw[512*16];   // head weights [i][o]
    __shared__ float s_hb[16];
    __shared__ float s_res[16][16];

    const int bt = blockIdx.x, t = threadIdx.x;
    const int wv = t >> 6, l = t & 63, ml = l & 15, kg = l >> 4;

    {   // d1
        f32x4 acc[8];
#pragma unroll
        for (int i = 0; i < 8; ++i) acc[i] = (f32x4){0.f,0.f,0.f,0.f};
        const u16* aB = xpk  + (size_t)bt*32768 + (size_t)l*8;
        const u16* wB = wd1p + (size_t)(wv*8)*32768 + (size_t)l*8;
#pragma unroll 2
        for (int kk = 0; kk < 64; ++kk) {
            bf16x8 a = *(const bf16x8*)(aB + (size_t)kk*512);
#pragma unroll
            for (int i = 0; i < 8; ++i) {
                bf16x8 w = *(const bf16x8*)(wB + (size_t)i*32768 + (size_t)kk*512);
                acc[i] = MFMA16(a, w, acc[i]);
            }
        }
#pragma unroll
        for (int i = 0; i < 8; ++i) {
            int nn = wv*128 + i*16 + ml;
            float bias = g_at<BF16>(bd1, nn);
            int sl = nn >> 3;
            int lo = (nn & 7) * 2;
#pragma unroll
            for (int r = 0; r < 4; ++r) {
                int box = kg*4 + r;
                u16 hv = f2b(fmaxf(acc[i][r] + bias, 0.f));
                *(u16*)((char*)s_d1 + box*1024 + (((sl ^ box) & 63) << 4) + lo) = hv;
            }
        }
    }
    __syncthreads();

    {   // d2
        f32x4 acc[8];
#pragma unroll
        for (int i = 0; i < 8; ++i) acc[i] = (f32x4){0.f,0.f,0.f,0.f};
        const u16* wB = wd2p + (size_t)(wv*8)*8192 + (size_t)l*8;
#pragma unroll 4
        for (int kk = 0; kk < 16; ++kk) {
            int sl = ((kk*4 + kg) ^ ml) & 63;
            bf16x8 a = *(const bf16x8*)((const char*)s_d1 + ml*1024 + (sl << 4));
#pragma unroll
            for (int i = 0; i < 8; ++i) {
                bf16x8 w = *(const bf16x8*)(wB + (size_t)i*8192 + (size_t)kk*512);
                acc[i] = MFMA16(a, w, acc[i]);
            }
        }
#pragma unroll
        for (int i = 0; i < 8; ++i) {
            int nn = wv*128 + i*16 + ml;
            float bias = g_at<BF16>(bd2, nn);
#pragma unroll
            for (int r = 0; r < 4; ++r) {
                int box = kg*4 + r;
                s_d2[box*516 + nn] = fmaxf(acc[i][r] + bias, 0.f);
            }
        }
    }
    // stage head weights: s_hw[i*16+o], o<12 from wr, 12..14 from wsc
    for (int idx = t; idx < 8192; idx += 256) {
        int i = idx >> 4, o = idx & 15;
        u16 v = 0;
        if (o < 12)      v = f2b(g_at<BF16>(wr, (size_t)i*12 + o));
        else if (o < 15) v = f2b(g_at<BF16>(wsc, (size_t)i*3 + o - 12));
        s_hw[idx] = v;
    }
    if (t < 16) s_hb[t] = (t < 12) ? g_at<BF16>(br, t) : (t < 15 ? g_at<BF16>(bsc, t-12) : 0.f);
    __syncthreads();

    {   // heads: thread (box = t>>4, o = t&15)
        int box = t >> 4, o = t & 15;
        float a = s_hb[o];
        const float* dp = &s_d2[box*516];
        for (int i = 0; i < 512; ++i) a += dp[i] * b2f(s_hw[i*16 + o]);
        s_res[box][o] = a;
    }
    __syncthreads();

    if (t < 16) {
        int n = n0 + bt*16 + t;
        if (n < N) {
            int c = cls[n];
            float fy1 = g_at<BF16>(boxes, (size_t)n*4+0);
            float fx1 = g_at<BF16>(boxes, (size_t)n*4+1);
            float fy2 = g_at<BF16>(boxes, (size_t)n*4+2);
            float fx2 = g_at<BF16>(boxes, (size_t)n*4+3);
            float sc = s_res[t][12 + c];
            float dy = s_res[t][c*4+0], dx = s_res[t][c*4+1];
            float dh = s_res[t][c*4+2], dw = s_res[t][c*4+3];
            g_st<BF16>(out, n, sc);
            g_st<BF16>(out, (size_t)N + n*4 + 0, dy);
            g_st<BF16>(out, (size_t)N + n*4 + 1, dx);
            g_st<BF16>(out, (size_t)N + n*4 + 2, dh);
            g_st<BF16>(out, (size_t)N + n*4 + 3, dw);
            float h = fy2 - fy1, w = fx2 - fx1;
            float cy = fy1 + 0.5f*h + dy*h;
            float cx = fx1 + 0.5f*w + dx*w;
            float nh = h * expf(dh);
            float nw = w * expf(dw);
            g_st<BF16>(out, (size_t)5*N + n*4 + 0, cy - 0.5f*nh);
            g_st<BF16>(out, (size_t)5*N + n*4 + 1, cx - 0.5f*nw);
            g_st<BF16>(out, (size_t)5*N + n*4 + 2, cy + 0.5f*nh);
            g_st<BF16>(out, (size_t)5*N + n*4 + 3, cx + 0.5f*nw);
        }
    }
}

extern "C" void kernel_launch(void* const* d_in, const int* in_sizes, int n_in,
                              void* d_out, int out_size, void* d_ws, size_t ws_size,
                              hipStream_t stream) {
    const void* feat  = d_in[0];
    const void* prop  = d_in[1];
    const void* boxes = d_in[2];
    const int*  bidx  = (const int*)d_in[3];
    const int*  cls   = (const int*)d_in[4];
    const void* w1  = d_in[5];
    const void* b1  = d_in[6];
    const void* w2  = d_in[7];
    const void* b2  = d_in[8];
    const void* wd1 = d_in[9];
    const void* bd1 = d_in[10];
    const void* wd2 = d_in[11];
    const void* bd2 = d_in[12];
    const void* wr  = d_in[13];
    const void* br  = d_in[14];
    const void* wsc = d_in[15];
    const void* bsc = d_in[16];
    const int N = in_sizes[3];   // boxes
    if (N <= 0) return;

    // workspace plan: weights 3.06 MB + 16-box x-tiles (64 KB each), chunked to fit
    size_t ws_elems = ws_size >> 1;
    long maxTiles = (ws_elems > (size_t)WS_X) ? (long)((ws_elems - WS_X) / 32768) : 0;
    long needTiles = (long)((N + 15) / 16);

    if (maxTiles > 0) {
        u16* ws = (u16*)d_ws;
        pack_weights<true ><<<748, 256, 0, stream>>>(boxes, w1, w2, wd1, wd2, ws);
        pack_weights<false><<<748, 256, 0, stream>>>(boxes, w1, w2, wd1, wd2, ws);
        long tilesPerChunk = maxTiles < needTiles ? maxTiles : needTiles;
        int chunk = (int)(tilesPerChunk * 16);
        for (int n0 = 0; n0 < N; n0 += chunk) {
            int cnt = (N - n0) < chunk ? (N - n0) : chunk;
            crop_conv<true ><<<cnt, 256, 0, stream>>>(feat, prop, boxes, bidx,
                                                      ws + WS_W1, ws + WS_W2, b1, b2,
                                                      ws + WS_X, n0, N);
            crop_conv<false><<<cnt, 256, 0, stream>>>(feat, prop, boxes, bidx,
                                                      ws + WS_W1, ws + WS_W2, b1, b2,
                                                      ws + WS_X, n0, N);
            int g16 = (cnt + 15) / 16;
            fc_head<true ><<<g16, 256, 0, stream>>>(boxes, cls, ws + WS_X,
                                                    ws + WS_WD1, bd1, ws + WS_WD2, bd2,
                                                    wr, br, wsc, bsc, d_out, n0, N);
            fc_head<false><<<g16, 256, 0, stream>>>(boxes, cls, ws + WS_X,
                                                    ws + WS_WD1, bd1, ws + WS_WD2, bd2,
                                                    wr, br, wsc, bsc, d_out, n0, N);
        }
    } else {
        // no usable workspace: legacy scalar kernels (self-gated by dtype)
        mask_head<true ><<<N, 256, 0, stream>>>(feat, prop, boxes, bidx, cls,
                                                w1, b1, w2, b2, wd1, bd1, wd2, bd2,
                                                wr, br, wsc, bsc, d_out, N);
        mask_head<false><<<N, 256, 0, stream>>>(feat, prop, boxes, bidx, cls,
                                                w1, b1, w2, b2, wd1, bd1, wd2, bd2,
                                                wr, br, wsc, bsc, d_out, N);
    }
}

// Round 3
// 874.672 us; speedup vs baseline: 4.0114x; 1.0144x over previous
//
#include <hip/hip_runtime.h>

typedef unsigned short u16;
typedef unsigned int   u32;

// ---- bf16 helpers (bit-level) ----
__device__ __forceinline__ float b2f(u16 v) {
    union { u32 i; float f; } u; u.i = ((u32)v) << 16; return u.f;
}
__device__ __forceinline__ float blo(u32 v) {
    union { u32 i; float f; } u; u.i = v << 16; return u.f;
}
__device__ __forceinline__ float bhi(u32 v) {
    union { u32 i; float f; } u; u.i = v & 0xffff0000u; return u.f;
}
__device__ __forceinline__ u16 f2b(float f) {   // RNE f32 -> bf16
    u32 x = __float_as_uint(f);
    u32 r = (x + 0x7fffu + ((x >> 16) & 1u)) >> 16;
    return (u16)r;
}

// ---- compile-time dtype accessors (legacy kernel + templated helpers) ----
template<bool BF16>
__device__ __forceinline__ float g_at(const void* p, size_t i) {
    if constexpr (BF16) return b2f(((const u16*)p)[i]);
    else                return ((const float*)p)[i];
}
template<bool BF16>
__device__ __forceinline__ float2 g_at2(const void* p, size_t i) {  // i even
    if constexpr (BF16) { u32 v = ((const u32*)p)[i >> 1]; return make_float2(blo(v), bhi(v)); }
    else                return ((const float2*)p)[i >> 1];
}
template<bool BF16>
__device__ __forceinline__ void g_st(void* p, size_t i, float v) {
    if constexpr (BF16) ((u16*)p)[i] = f2b(v);
    else                ((float*)p)[i] = v;
}

// ---- runtime dtype accessors (wave-uniform branch) ----
__device__ __forceinline__ float r_at(const void* p, size_t i, bool bf) {
    return bf ? b2f(((const u16*)p)[i]) : ((const float*)p)[i];
}
__device__ __forceinline__ void r_st(void* p, size_t i, float v, bool bf) {
    if (bf) ((u16*)p)[i] = f2b(v);
    else    ((float*)p)[i] = v;
}

// Detect packed-bf16 vs fp32 from the boxes buffer (values in (0,1]).
__device__ __forceinline__ bool detect_bf16(const void* boxes) {
    const u32* u = (const u32*)boxes;
    bool ok = true;
#pragma unroll
    for (int i = 0; i < 8; ++i) ok = ok && ((u[i] & 0xFFFFu) <= 0x3F80u);
    return ok;
}

#define HW 512
#define CIN 64
#define ZCROP (16*16*64)
#define ZC1   (8*8*128)

// =====================================================================
// Legacy scalar kernel (fallback when workspace is too small)
// =====================================================================
template<bool BF16>
__global__ __launch_bounds__(256, 2) void mask_head(
    const void* __restrict__ feat, const void* __restrict__ prop,
    const void* __restrict__ boxes, const int* __restrict__ bidx,
    const int* __restrict__ cls,
    const void* __restrict__ w1, const void* __restrict__ b1,
    const void* __restrict__ w2, const void* __restrict__ b2,
    const void* __restrict__ wd1, const void* __restrict__ bd1,
    const void* __restrict__ wd2, const void* __restrict__ bd2,
    const void* __restrict__ wr, const void* __restrict__ br,
    const void* __restrict__ wsc, const void* __restrict__ bsc,
    void* __restrict__ out, int N)
{
    if (detect_bf16(boxes) != BF16) return;

    __shared__ __align__(16) u16  s_crop[ZCROP + 128];
    __shared__ __align__(16) u16  s_c1[ZC1 + 128];
    __shared__ __align__(16) float s_c2[2048];
    __shared__ __align__(16) float s_d1[512];
    __shared__ __align__(16) float s_d2[512];
    __shared__ float s_prop[256];
    __shared__ float s_wy[16], s_wx[16];
    __shared__ int   s_y0[16], s_y1[16], s_x0[16], s_x1[16];
    __shared__ float s_reg[12], s_sc[3];

    const int n = blockIdx.x;
    if (n >= N) return;
    const int t = threadIdx.x;
    const int b = bidx[n];

    const float fy1 = g_at<BF16>(boxes, n*4+0);
    const float fx1 = g_at<BF16>(boxes, n*4+1);
    const float fy2 = g_at<BF16>(boxes, n*4+2);
    const float fx2 = g_at<BF16>(boxes, n*4+3);

    if (t < 16) {
        float g = (float)t * (1.0f / 15.0f);
        float yy = (fy1 + g * (fy2 - fy1)) * (float)(HW - 1);
        float xx = (fx1 + g * (fx2 - fx1)) * (float)(HW - 1);
        float yf = floorf(yy), xf = floorf(xx);
        s_wy[t] = yy - yf;  s_wx[t] = xx - xf;
        int y0 = min(max((int)yf, 0), HW-1);
        int x0 = min(max((int)xf, 0), HW-1);
        s_y0[t] = y0; s_y1[t] = min(y0 + 1, HW-1);
        s_x0[t] = x0; s_x1[t] = min(x0 + 1, HW-1);
    }
    if (t >= 128) s_crop[ZCROP + (t - 128)] = 0;
    if (t < 128)  s_c1[ZC1 + t] = 0;
    __syncthreads();

    {
        int py = t >> 4, px = t & 15;
        size_t pb = (size_t)b * (HW * HW);
        int y0 = s_y0[py], y1 = s_y1[py], x0 = s_x0[px], x1 = s_x1[px];
        float wy = s_wy[py], wx = s_wx[px];
        float p00 = g_at<BF16>(prop, pb + y0*HW + x0);
        float p01 = g_at<BF16>(prop, pb + y0*HW + x1);
        float p10 = g_at<BF16>(prop, pb + y1*HW + x0);
        float p11 = g_at<BF16>(prop, pb + y1*HW + x1);
        float top = p00 * (1.0f - wx) + p01 * wx;
        float bot = p10 * (1.0f - wx) + p11 * wx;
        s_prop[t] = top * (1.0f - wy) + bot * wy;
    }
    __syncthreads();

    {
        size_t fb = (size_t)b * ((size_t)HW * HW * CIN);
        const int ch = t & 63;
        const int wvl = t >> 6;
        for (int it = 0; it < 64; ++it) {
            int pix = it * 4 + wvl;
            int py = pix >> 4, px = pix & 15;
            int y0 = s_y0[py], y1 = s_y1[py], x0 = s_x0[px], x1 = s_x1[px];
            float wy = s_wy[py], wx = s_wx[px];
            float f00 = g_at<BF16>(feat, fb + (size_t)(y0*HW + x0)*CIN + ch);
            float f01 = g_at<BF16>(feat, fb + (size_t)(y0*HW + x1)*CIN + ch);
            float f10 = g_at<BF16>(feat, fb + (size_t)(y1*HW + x0)*CIN + ch);
            float f11 = g_at<BF16>(feat, fb + (size_t)(y1*HW + x1)*CIN + ch);
            float top = f00 * (1.0f - wx) + f01 * wx;
            float bot = f10 * (1.0f - wx) + f11 * wx;
            float v = (top * (1.0f - wy) + bot * wy) * s_prop[pix];
            s_crop[pix * 64 + ch] = f2b(v);
        }
    }
    __syncthreads();

    const int ocp = t & 63;
    const int wv  = t >> 6;

    {
        float2 bb = g_at2<BF16>(b1, 2*ocp);
        for (int it = 0; it < 4; ++it) {
            int g = it * 4 + wv;
            int oy = g >> 1;
            int oxb = (g & 1) * 4;
            float acc[4][2];
            #pragma unroll
            for (int p = 0; p < 4; ++p) { acc[p][0] = 0.f; acc[p][1] = 0.f; }
            #pragma unroll
            for (int ky = 0; ky < 3; ++ky) {
                int y = oy * 2 + ky;
                bool yv = (y < 16);
                #pragma unroll
                for (int kx = 0; kx < 3; ++kx) {
                    int off[4];
                    #pragma unroll
                    for (int p = 0; p < 4; ++p) {
                        int x = (oxb + p) * 2 + kx;
                        off[p] = (yv && x < 16) ? (y*16 + x) * 64 : ZCROP;
                    }
                    size_t wbase = ((size_t)(ky*3 + kx) * 64) * 128 + 2*ocp;
                    #pragma unroll 8
                    for (int ci = 0; ci < 64; ci += 2) {
                        float2 wa = g_at2<BF16>(w1, wbase + (size_t)ci*128);
                        float2 wb = g_at2<BF16>(w1, wbase + (size_t)(ci+1)*128);
                        #pragma unroll
                        for (int p = 0; p < 4; ++p) {
                            u32 cc = *(const u32*)&s_crop[off[p] + ci];
                            float v0 = blo(cc), v1 = bhi(cc);
                            acc[p][0] += v0 * wa.x + v1 * wb.x;
                            acc[p][1] += v0 * wa.y + v1 * wb.y;
                        }
                    }
                }
            }
            #pragma unroll
            for (int p = 0; p < 4; ++p) {
                int opix = oy * 8 + oxb + p;
                s_c1[opix * 128 + 2*ocp    ] = f2b(fmaxf(acc[p][0] + bb.x, 0.f));
                s_c1[opix * 128 + 2*ocp + 1] = f2b(fmaxf(acc[p][1] + bb.y, 0.f));
            }
        }
    }
    __syncthreads();

    {
        float2 bb = g_at2<BF16>(b2, 2*ocp);
        int oy = wv;
        float acc[4][2];
        #pragma unroll
        for (int p = 0; p < 4; ++p) { acc[p][0] = 0.f; acc[p][1] = 0.f; }
        #pragma unroll
        for (int ky = 0; ky < 3; ++ky) {
            int y = oy * 2 + ky;
            bool yv = (y < 8);
            #pragma unroll
            for (int kx = 0; kx < 3; ++kx) {
                int off[4];
                #pragma unroll
                for (int p = 0; p < 4; ++p) {
                    int x = p * 2 + kx;
                    off[p] = (yv && x < 8) ? (y*8 + x) * 128 : ZC1;
                }
                size_t wbase = ((size_t)(ky*3 + kx) * 128) * 128 + 2*ocp;
                #pragma unroll 8
                for (int ci = 0; ci < 128; ci += 2) {
                    float2 wa = g_at2<BF16>(w2, wbase + (size_t)ci*128);
                    float2 wb = g_at2<BF16>(w2, wbase + (size_t)(ci+1)*128);
                    #pragma unroll
                    for (int p = 0; p < 4; ++p) {
                        u32 cc = *(const u32*)&s_c1[off[p] + ci];
                        float v0 = blo(cc), v1 = bhi(cc);
                        acc[p][0] += v0 * wa.x + v1 * wb.x;
                        acc[p][1] += v0 * wa.y + v1 * wb.y;
                    }
                }
            }
        }
        #pragma unroll
        for (int p = 0; p < 4; ++p) {
            int opix = oy * 4 + p;
            s_c2[opix * 128 + 2*ocp    ] = fmaxf(acc[p][0] + bb.x, 0.f);
            s_c2[opix * 128 + 2*ocp + 1] = fmaxf(acc[p][1] + bb.y, 0.f);
        }
    }
    __syncthreads();

    {
        float acc0 = 0.f, acc1 = 0.f;
        for (int i = 0; i < 2048; i += 4) {
            float4 xv = *(const float4*)&s_c2[i];
            float2 u0 = g_at2<BF16>(wd1, (size_t)(i+0)*512 + 2*t);
            float2 u1 = g_at2<BF16>(wd1, (size_t)(i+1)*512 + 2*t);
            float2 u2 = g_at2<BF16>(wd1, (size_t)(i+2)*512 + 2*t);
            float2 u3 = g_at2<BF16>(wd1, (size_t)(i+3)*512 + 2*t);
            acc0 += xv.x*u0.x + xv.y*u1.x + xv.z*u2.x + xv.w*u3.x;
            acc1 += xv.x*u0.y + xv.y*u1.y + xv.z*u2.y + xv.w*u3.y;
        }
        float2 bb = g_at2<BF16>(bd1, 2*t);
        s_d1[2*t    ] = fmaxf(acc0 + bb.x, 0.f);
        s_d1[2*t + 1] = fmaxf(acc1 + bb.y, 0.f);
    }
    __syncthreads();

    {
        float acc0 = 0.f, acc1 = 0.f;
        for (int i = 0; i < 512; i += 4) {
            float4 xv = *(const float4*)&s_d1[i];
            float2 u0 = g_at2<BF16>(wd2, (size_t)(i+0)*512 + 2*t);
            float2 u1 = g_at2<BF16>(wd2, (size_t)(i+1)*512 + 2*t);
            float2 u2 = g_at2<BF16>(wd2, (size_t)(i+2)*512 + 2*t);
            float2 u3 = g_at2<BF16>(wd2, (size_t)(i+3)*512 + 2*t);
            acc0 += xv.x*u0.x + xv.y*u1.x + xv.z*u2.x + xv.w*u3.x;
            acc1 += xv.x*u0.y + xv.y*u1.y + xv.z*u2.y + xv.w*u3.y;
        }
        float2 bb = g_at2<BF16>(bd2, 2*t);
        s_d2[2*t    ] = fmaxf(acc0 + bb.x, 0.f);
        s_d2[2*t + 1] = fmaxf(acc1 + bb.y, 0.f);
    }
    __syncthreads();

    if (t < 12) {
        float a = g_at<BF16>(br, t);
        for (int i = 0; i < 512; ++i) a += s_d2[i] * g_at<BF16>(wr, (size_t)i*12 + t);
        s_reg[t] = a;
    }
    if (t >= 64 && t < 67) {
        int j = t - 64;
        float a = g_at<BF16>(bsc, j);
        for (int i = 0; i < 512; ++i) a += s_d2[i] * g_at<BF16>(wsc, (size_t)i*3 + j);
        s_sc[j] = a;
    }
    __syncthreads();

    if (t == 0) {
        int c = cls[n];
        g_st<BF16>(out, n, s_sc[c]);
        float dy = s_reg[c*4+0], dx = s_reg[c*4+1];
        float dh = s_reg[c*4+2], dw = s_reg[c*4+3];
        g_st<BF16>(out, (size_t)N + n*4 + 0, dy);
        g_st<BF16>(out, (size_t)N + n*4 + 1, dx);
        g_st<BF16>(out, (size_t)N + n*4 + 2, dh);
        g_st<BF16>(out, (size_t)N + n*4 + 3, dw);
        float h = fy2 - fy1, w = fx2 - fx1;
        float cy = fy1 + 0.5f*h + dy*h;
        float cx = fx1 + 0.5f*w + dx*w;
        float nh = h * expf(dh);
        float nw = w * expf(dw);
        g_st<BF16>(out, (size_t)5*N + n*4 + 0, cy - 0.5f*nh);
        g_st<BF16>(out, (size_t)5*N + n*4 + 1, cx - 0.5f*nw);
        g_st<BF16>(out, (size_t)5*N + n*4 + 2, cy + 0.5f*nh);
        g_st<BF16>(out, (size_t)5*N + n*4 + 3, cx + 0.5f*nw);
    }
}

// =====================================================================
// MFMA fast path — single kernels, runtime dtype branch (wave-uniform)
// =====================================================================
typedef __attribute__((ext_vector_type(8))) short bf16x8;   // 8 bf16 = 4 VGPRs
typedef __attribute__((ext_vector_type(4))) float f32x4;

__device__ __forceinline__ f32x4 MFMA16(bf16x8 a, bf16x8 b, f32x4 c) {
    return __builtin_amdgcn_mfma_f32_16x16x32_bf16(a, b, c, 0, 0, 0);
}

// workspace layout (u16 units)
#define WS_W1   0u          // w1 packed  : 73728
#define WS_W2   73728u      // w2 packed  : 147456
#define WS_WD1  221184u     // wd1 packed : 1048576
#define WS_WD2  1269760u    // wd2 packed : 262144
#define WS_X    1531904u    // conv2 out, d1-A-frag layout: tiles*32768

// Fragment packing: packed[((mt*KK + kk)*64 + l)*8 + j] = W[(kk*32 + (l>>4)*8 + j)*C + mt*16 + (l&15)]
template<bool BF>
__device__ __forceinline__ void pack_one(const void* __restrict__ W, u16* __restrict__ dst,
                                         int bid, int KK, int C) {
    int mt = bid / (KK*64);
    int kk = (bid >> 6) % KK;
    int l  = bid & 63;
    size_t s = (size_t)(kk*32 + ((l>>4)<<3))*C + mt*16 + (l&15);
    u16 tmp[8];
#pragma unroll
    for (int j = 0; j < 8; ++j) tmp[j] = f2b(g_at<BF>(W, s + (size_t)j*C));
    *(uint4*)(dst + (size_t)bid*8) = *(const uint4*)tmp;
}

template<bool BF>
__device__ __forceinline__ void pack_dispatch(
    int id, const void* w1, const void* w2, const void* wd1, const void* wd2,
    u16* ws)
{
    if      (id <   9216) pack_one<BF>(w1,  ws+WS_W1,  id,          18, 128);
    else if (id <  27648) pack_one<BF>(w2,  ws+WS_W2,  id-9216,     36, 128);
    else if (id < 158720) pack_one<BF>(wd1, ws+WS_WD1, id-27648,    64, 512);
    else if (id < 191488) pack_one<BF>(wd2, ws+WS_WD2, id-158720,   16, 512);
}

__global__ __launch_bounds__(256) void pack_weights(
    const void* __restrict__ boxes,
    const void* __restrict__ w1, const void* __restrict__ w2,
    const void* __restrict__ wd1, const void* __restrict__ wd2,
    u16* __restrict__ ws)
{
    int id = blockIdx.x*256 + threadIdx.x;
    if (detect_bf16(boxes)) pack_dispatch<true >(id, w1, w2, wd1, wd2, ws);
    else                    pack_dispatch<false>(id, w1, w2, wd1, wd2, ws);
}

// Bilinear feature gather, 4 channels/lane, 16 lanes/pixel-corner.
template<bool BF>
__device__ __forceinline__ void gather_feat(
    const void* __restrict__ feat, size_t fbase, int t,
    const float* s_wy, const float* s_wx,
    const int* s_y0, const int* s_y1, const int* s_x0, const int* s_x1,
    const float* s_prop, u16* s_crop)
{
    const int cq = t & 15;          // channel quad: ch = cq*4..cq*4+3
    const int g  = t >> 4;          // pixel slot 0..15
    const size_t fb = fbase + (size_t)cq*4;
#pragma unroll 2
    for (int it = 0; it < 16; ++it) {
        int pix = it*16 + g;
        int py = pix >> 4, px = pix & 15;
        int y0 = s_y0[py], y1 = s_y1[py], x0 = s_x0[px], x1 = s_x1[px];
        float wy = s_wy[py], wx = s_wx[px];
        float4 c00, c01, c10, c11;
        if constexpr (BF) {
            uint2 v00 = *(const uint2*)((const u16*)feat + fb + (size_t)(y0*HW + x0)*CIN);
            uint2 v01 = *(const uint2*)((const u16*)feat + fb + (size_t)(y0*HW + x1)*CIN);
            uint2 v10 = *(const uint2*)((const u16*)feat + fb + (size_t)(y1*HW + x0)*CIN);
            uint2 v11 = *(const uint2*)((const u16*)feat + fb + (size_t)(y1*HW + x1)*CIN);
            c00 = make_float4(blo(v00.x), bhi(v00.x), blo(v00.y), bhi(v00.y));
            c01 = make_float4(blo(v01.x), bhi(v01.x), blo(v01.y), bhi(v01.y));
            c10 = make_float4(blo(v10.x), bhi(v10.x), blo(v10.y), bhi(v10.y));
            c11 = make_float4(blo(v11.x), bhi(v11.x), blo(v11.y), bhi(v11.y));
        } else {
            c00 = *(const float4*)((const float*)feat + fb + (size_t)(y0*HW + x0)*CIN);
            c01 = *(const float4*)((const float*)feat + fb + (size_t)(y0*HW + x1)*CIN);
            c10 = *(const float4*)((const float*)feat + fb + (size_t)(y1*HW + x0)*CIN);
            c11 = *(const float4*)((const float*)feat + fb + (size_t)(y1*HW + x1)*CIN);
        }
        float pv = s_prop[pix];
        float omx = 1.f - wx, omy = 1.f - wy;
        float t0 = c00.x*omx + c01.x*wx, b0 = c10.x*omx + c11.x*wx;
        float t1 = c00.y*omx + c01.y*wx, b1 = c10.y*omx + c11.y*wx;
        float t2 = c00.z*omx + c01.z*wx, b2 = c10.z*omx + c11.z*wx;
        float t3 = c00.w*omx + c01.w*wx, b3 = c10.w*omx + c11.w*wx;
        float v0 = (t0*omy + b0*wy) * pv;
        float v1 = (t1*omy + b1*wy) * pv;
        float v2 = (t2*omy + b2*wy) * pv;
        float v3 = (t3*omy + b3*wy) * pv;
        u32 pk0 = (u32)f2b(v0) | ((u32)f2b(v1) << 16);
        u32 pk1 = (u32)f2b(v2) | ((u32)f2b(v3) << 16);
        // pair idx cp0 = 2*cq, cp0+1 share a 16B slot; same swizzle image as before
        int off = pix*128 + ((((cq>>1) ^ ((pix>>1)&7)) & 7) << 4) + (cq&1)*8;
        *(uint2*)((char*)s_crop + off) = make_uint2(pk0, pk1);
    }
}

// K1: crop+prop-mul -> conv1 (MFMA) -> conv2 (MFMA) -> x_packed (d1 A-frag layout)
__global__ __launch_bounds__(256, 2) void crop_conv(
    const void* __restrict__ feat, const void* __restrict__ prop,
    const void* __restrict__ boxes, const int* __restrict__ bidx,
    const u16* __restrict__ w1p, const u16* __restrict__ w2p,
    const void* __restrict__ cb1, const void* __restrict__ cb2,
    u16* __restrict__ xpk, int n0, int N)
{
    const bool isbf = detect_bf16(boxes);
    __shared__ __align__(16) u16 s_crop[257*64];
    __shared__ __align__(16) u16 s_c1[65*128];
    __shared__ float s_prop[256];
    __shared__ float s_wy[16], s_wx[16];
    __shared__ int   s_y0[16], s_y1[16], s_x0[16], s_x1[16];

    const int nloc = blockIdx.x;
    const int n = n0 + nloc;
    const int t = threadIdx.x;
    const int b = bidx[n];
    const float fy1 = r_at(boxes, (size_t)n*4+0, isbf);
    const float fx1 = r_at(boxes, (size_t)n*4+1, isbf);
    const float fy2 = r_at(boxes, (size_t)n*4+2, isbf);
    const float fx2 = r_at(boxes, (size_t)n*4+3, isbf);

    if (t < 16) {
        float g = (float)t * (1.0f / 15.0f);
        float yy = (fy1 + g * (fy2 - fy1)) * (float)(HW - 1);
        float xx = (fx1 + g * (fx2 - fx1)) * (float)(HW - 1);
        float yf = floorf(yy), xf = floorf(xx);
        s_wy[t] = yy - yf;  s_wx[t] = xx - xf;
        int y0 = min(max((int)yf, 0), HW-1);
        int x0 = min(max((int)xf, 0), HW-1);
        s_y0[t] = y0; s_y1[t] = min(y0 + 1, HW-1);
        s_x0[t] = x0; s_x1[t] = min(x0 + 1, HW-1);
    }
    // zero pad rows (row 256 of s_crop, row 64 of s_c1)
    if (t < 32)              ((u32*)s_crop)[256*32 + t]      = 0;
    if (t >= 64 && t < 128)  ((u32*)s_c1)[64*64 + (t - 64)]  = 0;
    __syncthreads();

    {   // proposal crop
        int py = t >> 4, px = t & 15;
        size_t pb = (size_t)b * (HW * HW);
        int y0 = s_y0[py], y1 = s_y1[py], x0 = s_x0[px], x1 = s_x1[px];
        float wy = s_wy[py], wx = s_wx[px];
        float p00 = r_at(prop, pb + y0*HW + x0, isbf);
        float p01 = r_at(prop, pb + y0*HW + x1, isbf);
        float p10 = r_at(prop, pb + y1*HW + x0, isbf);
        float p11 = r_at(prop, pb + y1*HW + x1, isbf);
        float top = p00*(1.f-wx) + p01*wx;
        float bot = p10*(1.f-wx) + p11*wx;
        s_prop[t] = top*(1.f-wy) + bot*wy;
    }
    __syncthreads();

    {   // feature crop * prop -> s_crop
        size_t fbase = (size_t)b * ((size_t)HW*HW*CIN);
        if (isbf) gather_feat<true >(feat, fbase, t, s_wy, s_wx, s_y0, s_y1, s_x0, s_x1, s_prop, s_crop);
        else      gather_feat<false>(feat, fbase, t, s_wy, s_wx, s_y0, s_y1, s_x0, s_x1, s_prop, s_crop);
    }
    __syncthreads();

    const int wv = t >> 6, l = t & 63, ml = l & 15, kg = l >> 4;

    {   // conv1: M=128 out-ch (A=W1^T, global packed), N=64 pixels (B=im2col, LDS), K=576
        f32x4 acc[2][4];
#pragma unroll
        for (int am = 0; am < 2; ++am)
#pragma unroll
            for (int nt = 0; nt < 4; ++nt) acc[am][nt] = (f32x4){0.f,0.f,0.f,0.f};
        const int oyb = (ml>>3)*2, ox2v = (ml&7)*2;
        const u16* aP0 = w1p + (size_t)(wv*2+0)*9216 + (size_t)l*8;
        const u16* aP1 = w1p + (size_t)(wv*2+1)*9216 + (size_t)l*8;
#pragma unroll
        for (int tap = 0; tap < 9; ++tap) {
            const int ky = tap/3, kx = tap%3;
            int bB[4];
            {
                int x = ox2v + kx;
                bool xv = (x < 16);
#pragma unroll
                for (int nt = 0; nt < 4; ++nt) {
                    int y = nt*4 + oyb + ky;
                    int sp = (xv && y < 16) ? (y*16 + x) : 256;
                    bB[nt] = (sp << 7) | (((sp >> 1) & 7) << 4);
                }
            }
#pragma unroll
            for (int h = 0; h < 2; ++h) {
                const int kk = tap*2 + h;
                const int cisb = (h*4 + kg) << 4;
                bf16x8 a0 = *(const bf16x8*)(aP0 + kk*512);
                bf16x8 a1 = *(const bf16x8*)(aP1 + kk*512);
#pragma unroll
                for (int nt = 0; nt < 4; ++nt) {
                    bf16x8 bfr = *(const bf16x8*)((const char*)s_crop + (bB[nt] ^ cisb));
                    acc[0][nt] = MFMA16(a0, bfr, acc[0][nt]);
                    acc[1][nt] = MFMA16(a1, bfr, acc[1][nt]);
                }
            }
        }
        // epilogue: bias+relu -> s_c1 (swizzled, 8B stores of 4 consecutive channels)
#pragma unroll
        for (int am = 0; am < 2; ++am) {
            const int ch0 = wv*32 + am*16 + kg*4;
            float bias[4];
#pragma unroll
            for (int r = 0; r < 4; ++r) bias[r] = r_at(cb1, ch0 + r, isbf);
            const int sl = (ch0 >> 3) << 4;
            const int lo = (ch0 & 7) * 2;
#pragma unroll
            for (int nt = 0; nt < 4; ++nt) {
                int p = nt*16 + ml;
                u16 pk[4];
#pragma unroll
                for (int r = 0; r < 4; ++r) pk[r] = f2b(fmaxf(acc[am][nt][r] + bias[r], 0.f));
                int g2 = ((((p>>1)&3) | (((p>>4)&3)<<2))) << 4;
                int off = p*256 + (sl ^ g2) + lo;
                *(uint2*)((char*)s_c1 + off) = *(const uint2*)pk;
            }
        }
    }
    __syncthreads();

    {   // conv2: M=128 out-ch, N=16 pixels, K=1152
        f32x4 acc[2];
        acc[0] = (f32x4){0.f,0.f,0.f,0.f};
        acc[1] = (f32x4){0.f,0.f,0.f,0.f};
        const int oyb = (ml>>2)*2, ox2v = (ml&3)*2;
        const u16* aP0 = w2p + (size_t)(wv*2+0)*18432 + (size_t)l*8;
        const u16* aP1 = w2p + (size_t)(wv*2+1)*18432 + (size_t)l*8;
#pragma unroll
        for (int tap = 0; tap < 9; ++tap) {
            const int ky = tap/3, kx = tap%3;
            int y = oyb + ky, x = ox2v + kx;
            int sp = (y < 8 && x < 8) ? (y*8 + x) : 64;
            int bB = sp*256 + (((((sp>>1)&3) | (((sp>>4)&3)<<2))) << 4);
#pragma unroll
            for (int q = 0; q < 4; ++q) {
                const int kk = tap*4 + q;
                const int slb = (q*4 + kg) << 4;
                bf16x8 bfr = *(const bf16x8*)((const char*)s_c1 + (bB ^ slb));
                bf16x8 a0 = *(const bf16x8*)(aP0 + kk*512);
                bf16x8 a1 = *(const bf16x8*)(aP1 + kk*512);
                acc[0] = MFMA16(a0, bfr, acc[0]);
                acc[1] = MFMA16(a1, bfr, acc[1]);
            }
        }
        // epilogue: bias+relu -> xpk directly in the d1 A-fragment layout
        const size_t bt = (size_t)(nloc >> 4), bl = (size_t)(nloc & 15);
#pragma unroll
        for (int am = 0; am < 2; ++am) {
            const int ch0 = wv*32 + am*16 + kg*4;
            u16 pk[4];
#pragma unroll
            for (int r = 0; r < 4; ++r)
                pk[r] = f2b(fmaxf(acc[am][r] + r_at(cb2, ch0 + r, isbf), 0.f));
            size_t dst = (bt*64 + (size_t)ml*4 + (size_t)(ch0>>5))*512
                       + (size_t)((ch0 & 31) >> 3)*128 + bl*8 + (size_t)(ch0 & 7);
            *(uint2*)(xpk + dst) = *(const uint2*)pk;
        }
    }
}

// K2: d1 (16x2048 x 2048x512) + d2 (16x512 x 512x512) + heads, per 16-box tile
__global__ __launch_bounds__(256, 2) void fc_head(
    const void* __restrict__ boxes, const int* __restrict__ cls,
    const u16* __restrict__ xpk,
    const u16* __restrict__ wd1p, const void* __restrict__ bd1,
    const u16* __restrict__ wd2p, const void* __restrict__ bd2,
    const void* __restrict__ wr,  const void* __restrict__ br,
    const void* __restrict__ wsc, const void* __restrict__ bsc,
    void* __restrict__ out, int n0, int N)
{
    const bool isbf = detect_bf16(boxes);
    __shared__ __align__(16) u16  s_d1[16*512];   // bf16, 1024B rows, XOR slot swizzle
    __shared__ __align__(16) float s_d2[16*516];  // f32, padded rows
    __shared__ __align__(16) u16  s_hw[512*16];   // head weights [i][o]
    __shared__ float s_hb[16];
    __shared__ float s_res[16][16];

    const int bt = blockIdx.x, t = threadIdx.x;
    const int wv = t >> 6, l = t & 63, ml = l & 15, kg = l >> 4;

    {   // d1
        f32x4 acc[8];
#pragma unroll
        for (int i = 0; i < 8; ++i) acc[i] = (f32x4){0.f,0.f,0.f,0.f};
        const u16* aB = xpk  + (size_t)bt*32768 + (size_t)l*8;
        const u16* wB = wd1p + (size_t)(wv*8)*32768 + (size_t)l*8;
#pragma unroll 2
        for (int kk = 0; kk < 64; ++kk) {
            bf16x8 a = *(const bf16x8*)(aB + (size_t)kk*512);
#pragma unroll
            for (int i = 0; i < 8; ++i) {
                bf16x8 w = *(const bf16x8*)(wB + (size_t)i*32768 + (size_t)kk*512);
                acc[i] = MFMA16(a, w, acc[i]);
            }
        }
#pragma unroll
        for (int i = 0; i < 8; ++i) {
            int nn = wv*128 + i*16 + ml;
            float bias = r_at(bd1, nn, isbf);
            int sl = nn >> 3;
            int lo = (nn & 7) * 2;
#pragma unroll
            for (int r = 0; r < 4; ++r) {
                int box = kg*4 + r;
                u16 hv = f2b(fmaxf(acc[i][r] + bias, 0.f));
                *(u16*)((char*)s_d1 + box*1024 + (((sl ^ box) & 63) << 4) + lo) = hv;
            }
        }
    }
    __syncthreads();

    {   // d2
        f32x4 acc[8];
#pragma unroll
        for (int i = 0; i < 8; ++i) acc[i] = (f32x4){0.f,0.f,0.f,0.f};
        const u16* wB = wd2p + (size_t)(wv*8)*8192 + (size_t)l*8;
#pragma unroll 4
        for (int kk = 0; kk < 16; ++kk) {
            int sl = ((kk*4 + kg) ^ ml) & 63;
            bf16x8 a = *(const bf16x8*)((const char*)s_d1 + ml*1024 + (sl << 4));
#pragma unroll
            for (int i = 0; i < 8; ++i) {
                bf16x8 w = *(const bf16x8*)(wB + (size_t)i*8192 + (size_t)kk*512);
                acc[i] = MFMA16(a, w, acc[i]);
            }
        }
#pragma unroll
        for (int i = 0; i < 8; ++i) {
            int nn = wv*128 + i*16 + ml;
            float bias = r_at(bd2, nn, isbf);
#pragma unroll
            for (int r = 0; r < 4; ++r) {
                int box = kg*4 + r;
                s_d2[box*516 + nn] = fmaxf(acc[i][r] + bias, 0.f);
            }
        }
    }
    // stage head weights: s_hw[i*16+o], o<12 from wr, 12..14 from wsc
    for (int idx = t; idx < 8192; idx += 256) {
        int i = idx >> 4, o = idx & 15;
        u16 v = 0;
        if (o < 12)      v = f2b(r_at(wr, (size_t)i*12 + o, isbf));
        else if (o < 15) v = f2b(r_at(wsc, (size_t)i*3 + o - 12, isbf));
        s_hw[idx] = v;
    }
    if (t < 16) s_hb[t] = (t < 12) ? r_at(br, t, isbf) : (t < 15 ? r_at(bsc, t-12, isbf) : 0.f);
    __syncthreads();

    {   // heads: thread (box = t>>4, o = t&15)
        int box = t >> 4, o = t & 15;
        float a = s_hb[o];
        const float* dp = &s_d2[box*516];
        for (int i = 0; i < 512; ++i) a += dp[i] * b2f(s_hw[i*16 + o]);
        s_res[box][o] = a;
    }
    __syncthreads();

    if (t < 16) {
        int n = n0 + bt*16 + t;
        if (n < N) {
            int c = cls[n];
            float fy1 = r_at(boxes, (size_t)n*4+0, isbf);
            float fx1 = r_at(boxes, (size_t)n*4+1, isbf);
            float fy2 = r_at(boxes, (size_t)n*4+2, isbf);
            float fx2 = r_at(boxes, (size_t)n*4+3, isbf);
            float sc = s_res[t][12 + c];
            float dy = s_res[t][c*4+0], dx = s_res[t][c*4+1];
            float dh = s_res[t][c*4+2], dw = s_res[t][c*4+3];
            r_st(out, n, sc, isbf);
            r_st(out, (size_t)N + n*4 + 0, dy, isbf);
            r_st(out, (size_t)N + n*4 + 1, dx, isbf);
            r_st(out, (size_t)N + n*4 + 2, dh, isbf);
            r_st(out, (size_t)N + n*4 + 3, dw, isbf);
            float h = fy2 - fy1, w = fx2 - fx1;
            float cy = fy1 + 0.5f*h + dy*h;
            float cx = fx1 + 0.5f*w + dx*w;
            float nh = h * expf(dh);
            float nw = w * expf(dw);
            r_st(out, (size_t)5*N + n*4 + 0, cy - 0.5f*nh, isbf);
            r_st(out, (size_t)5*N + n*4 + 1, cx - 0.5f*nw, isbf);
            r_st(out, (size_t)5*N + n*4 + 2, cy + 0.5f*nh, isbf);
            r_st(out, (size_t)5*N + n*4 + 3, cx + 0.5f*nw, isbf);
        }
    }
}

extern "C" void kernel_launch(void* const* d_in, const int* in_sizes, int n_in,
                              void* d_out, int out_size, void* d_ws, size_t ws_size,
                              hipStream_t stream) {
    const void* feat  = d_in[0];
    const void* prop  = d_in[1];
    const void* boxes = d_in[2];
    const int*  bidx  = (const int*)d_in[3];
    const int*  cls   = (const int*)d_in[4];
    const void* w1  = d_in[5];
    const void* b1  = d_in[6];
    const void* w2  = d_in[7];
    const void* b2  = d_in[8];
    const void* wd1 = d_in[9];
    const void* bd1 = d_in[10];
    const void* wd2 = d_in[11];
    const void* bd2 = d_in[12];
    const void* wr  = d_in[13];
    const void* br  = d_in[14];
    const void* wsc = d_in[15];
    const void* bsc = d_in[16];
    const int N = in_sizes[3];   // boxes
    if (N <= 0) return;

    // workspace plan: weights ~3 MB + 16-box x-tiles (64 KB each), chunked to fit
    size_t ws_elems = ws_size >> 1;
    long maxTiles = (ws_elems > (size_t)WS_X) ? (long)((ws_elems - WS_X) / 32768) : 0;
    long needTiles = (long)((N + 15) / 16);

    if (maxTiles > 0) {
        u16* ws = (u16*)d_ws;
        pack_weights<<<748, 256, 0, stream>>>(boxes, w1, w2, wd1, wd2, ws);
        long tilesPerChunk = maxTiles < needTiles ? maxTiles : needTiles;
        int chunk = (int)(tilesPerChunk * 16);
        for (int n0 = 0; n0 < N; n0 += chunk) {
            int cnt = (N - n0) < chunk ? (N - n0) : chunk;
            crop_conv<<<cnt, 256, 0, stream>>>(feat, prop, boxes, bidx,
                                               ws + WS_W1, ws + WS_W2, b1, b2,
                                               ws + WS_X, n0, N);
            int g16 = (cnt + 15) / 16;
            fc_head<<<g16, 256, 0, stream>>>(boxes, cls, ws + WS_X,
                                             ws + WS_WD1, bd1, ws + WS_WD2, bd2,
                                             wr, br, wsc, bsc, d_out, n0, N);
        }
    } else {
        // no usable workspace: legacy scalar kernels (self-gated by dtype)
        mask_head<true ><<<N, 256, 0, stream>>>(feat, prop, boxes, bidx, cls,
                                                w1, b1, w2, b2, wd1, bd1, wd2, bd2,
                                                wr, br, wsc, bsc, d_out, N);
        mask_head<false><<<N, 256, 0, stream>>>(feat, prop, boxes, bidx, cls,
                                                w1, b1, w2, b2, wd1, bd1, wd2, bd2,
                                                wr, br, wsc, bsc, d_out, N);
    }
}